// Round 14
// baseline (728.138 us; speedup 1.0000x reference)
//
#include <hip/hip_runtime.h>
#include <hip/hip_bf16.h>

// ---------------------------------------------------------------------------
// C4 equivariant CNN, round 14: r13 + K-fold for conv1.
//  conv1 (IC=24 padded to 32 -> 25% zero MFMA work) now folds kx into the
//  GEMM K dim: 5 ky-steps x K=120->128 (6.7% pad) = 20 MFMA blocks vs 25.
//  Single staging pass (all 24ch hi+lo in the 8-chunk swizzled stride),
//  fully unrolled 20-step loop with SSA B double-buffer.
//  conv2..5 unchanged (r13 PMODE split).
// ---------------------------------------------------------------------------

typedef short s16x8 __attribute__((ext_vector_type(8)));
typedef __bf16 bf16x8 __attribute__((ext_vector_type(8)));
typedef float f32x4 __attribute__((ext_vector_type(4)));
typedef unsigned short u16;
typedef unsigned int u32;

__device__ __forceinline__ u16 f2bf(float f) {      // RNE fp32 -> bf16 bits
    unsigned u = __float_as_uint(f);
    return (u16)((u + 0x7FFFu + ((u >> 16) & 1u)) >> 16);
}
__device__ __forceinline__ float bf2f(u16 h) {
    return __uint_as_float(((unsigned)h) << 16);
}

__device__ __forceinline__ void rot_src(int r, int K, int y, int x, int& sy, int& sx) {
    switch (r & 3) {
        case 0: sy = y;         sx = x;         break;
        case 1: sy = x;         sx = K - 1 - y; break;
        case 2: sy = K - 1 - y; sx = K - 1 - x; break;
        default: sy = K - 1 - x; sx = y;        break;
    }
}

// w0: (6,1,7,7) -> F0T: [49][24] fp32
__global__ void lift_w0T_kernel(const float* __restrict__ w, float* __restrict__ f) {
    const int K = 7, KK = 49, OC = 24;
    int idx = blockIdx.x * blockDim.x + threadIdx.x;
    if (idx >= KK * OC) return;
    int oc = idx % OC; int kk = idx / OC;
    int y = kk / K, x = kk % K;
    int r = oc & 3, o = oc >> 2;
    int sy, sx; rot_src(r, K, y, x, sy, sx);
    f[idx] = w[o * KK + sy * K + sx];
}

// group-transform + split + pack into MFMA B-fragment order (windowed form).
__global__ void wfrag_kernel(const float* __restrict__ w, u16* __restrict__ wf,
                             int O, int I, int KC, int NT, int total) {
    int idx = blockIdx.x * blockDim.x + threadIdx.x;
    if (idx >= total) return;
    int j = idx & 7;
    int lane = (idx >> 3) & 63;
    int rest = idx >> 9;
    int nc = rest % NT; rest /= NT;
    int kc = rest % KC; int kpos = rest / KC;
    int ky = kpos / 5, kx = kpos % 5;
    int kk = ((lane >> 4) << 3) + j;
    int ic = kc * 32 + kk;
    int oc = nc * 16 + (lane & 15);
    float val = 0.f;
    if (ic < I * 4) {
        int o = oc >> 2, r = oc & 3, i = ic >> 2, s = ic & 3;
        int g = (s - r + 4) & 3;
        int sy, sx; rot_src(r, 5, ky, kx, sy, sx);
        val = w[(((o * I + i) * 4 + g) * 25) + sy * 5 + sx];
    }
    u16 hb = f2bf(val);
    u16 lb = f2bf(val - bf2f(hb));
    wf[idx] = hb;
    wf[idx + total] = lb;
}

// K-fold variant: step = ky*PASSES + p; within a pass k = (lane>>4)*8 + j,
// global kchunk = p*4 + (lane>>4); kx = kchunk/ICR8, ic = (kchunk%ICR8)*8+j.
__global__ void wfrag_fold_kernel(const float* __restrict__ w, u16* __restrict__ wf,
                                  int O, int I, int PASSES, int NT, int ICR8,
                                  int total) {
    int idx = blockIdx.x * blockDim.x + threadIdx.x;
    if (idx >= total) return;
    int j = idx & 7;
    int lane = (idx >> 3) & 63;
    int rest = idx >> 9;
    int nc = rest % NT; rest /= NT;
    int p = rest % PASSES; int ky = rest / PASSES;
    int kchunk = p * 4 + (lane >> 4);
    float val = 0.f;
    if (kchunk < 5 * ICR8) {
        int kx = kchunk / ICR8;
        int icc = kchunk - kx * ICR8;
        int ic = icc * 8 + j;                     // < ICR8*8 = real IC
        int oc = nc * 16 + (lane & 15);
        int o = oc >> 2, r = oc & 3, i = ic >> 2, s = ic & 3;
        int g = (s - r + 4) & 3;
        int sy, sx; rot_src(r, 5, ky, kx, sy, sx);
        val = w[(((o * I + i) * 4 + g) * 25) + sy * 5 + sx];
    }
    u16 hb = f2bf(val);
    u16 lb = f2bf(val - bf2f(hb));
    wf[idx] = hb;
    wf[idx + total] = lb;
}

// x (64,1,96,96) -> xp (64, 98, 100) fp32 with 1-border (pre-zeroed)
__global__ void pad_x_kernel(const float* __restrict__ x, float* __restrict__ xp) {
    int idx = blockIdx.x * blockDim.x + threadIdx.x;
    if (idx >= 64 * 96 * 96) return;
    int c = idx % 96; int t = idx / 96;
    int r = t % 96; int n = t / 96;
    xp[((size_t)n * 98 + r + 1) * 100 + c + 1] = x[idx];
}

// zero the 2-thick halo border only (both planes); interior written by convs
__global__ void prep_halo_kernel(u16* __restrict__ buf, long LO, int NHW,
                                 int Hp, int Wp, int ICO) {
    int idx = blockIdx.x * blockDim.x + threadIdx.x;
    if (idx >= NHW) return;
    int c = idx % Wp; int t = idx / Wp;
    int r = t % Hp; int n = t / Hp;
    bool halo = (r < 2) || (r >= Hp - 2) || (c < 2) || (c >= Wp - 2);
    if (!halo) return;
    size_t base = (((size_t)n * Hp + r) * Wp + c) * ICO;
    s16x8 z = {0, 0, 0, 0, 0, 0, 0, 0};
    for (int cc = 0; cc < (ICO >> 3); ++cc) {
        *(s16x8*)(buf + base + cc * 8) = z;
        *(s16x8*)(buf + LO + base + cc * 8) = z;
    }
}

// conv0: fp32 direct (IC=1, K=7, pad=1). One thread: ALL 24 oc x 4 x.
// P1: [64][96][96][24] hi|lo, halo 2. Full 48B lines per pixel.
__global__ __launch_bounds__(256) void conv0_kernel(
        const float* __restrict__ xp, const float* __restrict__ f0t,
        const float* __restrict__ b0, u16* __restrict__ p1, long p1LO) {
    int idx = blockIdx.x * blockDim.x + threadIdx.x;
    if (idx >= 64 * 92 * 23) return;
    int xq = idx % 23; int t = idx / 23;
    int oy = t % 92; int n = t / 92;
    float acc[24][4];
#pragma unroll
    for (int a = 0; a < 24; ++a)
#pragma unroll
        for (int b = 0; b < 4; ++b) acc[a][b] = 0.f;

    const float* ip = xp + ((size_t)n * 98 + oy) * 100 + xq * 4;
#pragma unroll
    for (int ky = 0; ky < 7; ++ky) {
        const float* row = ip + (size_t)ky * 100;
        float xv[12];
#pragma unroll
        for (int v = 0; v < 3; ++v)
            *reinterpret_cast<float4*>(&xv[4 * v]) =
                *reinterpret_cast<const float4*>(row + 4 * v);
#pragma unroll
        for (int kx = 0; kx < 7; ++kx) {
            const float* wp = f0t + (ky * 7 + kx) * 24;
#pragma unroll
            for (int qd = 0; qd < 6; ++qd) {
                float4 wv = *reinterpret_cast<const float4*>(wp + qd * 4);
#pragma unroll
                for (int jx = 0; jx < 4; ++jx) {
                    acc[qd * 4 + 0][jx] = fmaf(wv.x, xv[kx + jx], acc[qd * 4 + 0][jx]);
                    acc[qd * 4 + 1][jx] = fmaf(wv.y, xv[kx + jx], acc[qd * 4 + 1][jx]);
                    acc[qd * 4 + 2][jx] = fmaf(wv.z, xv[kx + jx], acc[qd * 4 + 2][jx]);
                    acc[qd * 4 + 3][jx] = fmaf(wv.w, xv[kx + jx], acc[qd * 4 + 3][jx]);
                }
            }
        }
    }
    float bv[6];
#pragma unroll
    for (int qd = 0; qd < 6; ++qd) bv[qd] = b0[qd];

    size_t ob = (((size_t)n * 96 + oy + 2) * 96 + xq * 4 + 2) * 24;
#pragma unroll
    for (int jx = 0; jx < 4; ++jx) {
        s16x8 hv[3], lv[3];
#pragma unroll
        for (int cc = 0; cc < 3; ++cc)
#pragma unroll
            for (int e = 0; e < 8; ++e) {
                int ch = cc * 8 + e;
                float v = fmaxf(acc[ch][jx] + bv[ch >> 2], 0.f);
                u16 hb = f2bf(v);
                u16 lb = f2bf(v - bf2f(hb));
                hv[cc][e] = (short)hb; lv[cc][e] = (short)lb;
            }
#pragma unroll
        for (int cc = 0; cc < 3; ++cc) {
            *(s16x8*)(p1 + ob + jx * 24 + cc * 8) = hv[cc];
            *(s16x8*)(p1 + p1LO + ob + jx * 24 + cc * 8) = lv[cc];
        }
    }
}

// ---------------------------------------------------------------------------
// K-FOLD MFMA conv (conv1): kx folded into K. Stage all ICIN once (hi+lo in
// 8-chunk swizzled stride), then 5*PASSES fully-unrolled steps.
// ---------------------------------------------------------------------------
template <int ICR8, int ICIN, int PASSES, int NT, int NTW, int MT, int CR, int SW,
          bool POOL, int XOFF, int OCO, bool TRANS>
__global__ __launch_bounds__(SW*(NT/NTW)*64, 2) void conv_fold_kernel(
        const u16* __restrict__ act, long actLO,
        const u16* __restrict__ wf, int wfLO,
        const float* __restrict__ bias,
        u16* __restrict__ outP, long outLO,
        float* __restrict__ outF,
        int Hp, int Wp, int OH, int OW, int PH, int POW,
        int NRG, int NXS, int HpO, int WpO) {
    constexpr int OG = NT / NTW;
    constexpr int NW = SW * OG;
    constexpr int WT = MT * 16 + 4 + XOFF;
    constexpr int R  = CR * SW + 4;
    constexpr int CHUNKS = R * WT * 8;
    constexpr int TROWS = POOL ? SW : CR * SW;
    constexpr int TX = POOL ? MT * 8 : MT * 16;
    constexpr int SX = OCO + 4;
    constexpr int STAGE_B = CHUNKS * 16;
    constexpr int TRAN_B = TRANS ? TROWS * TX * SX * 4 : 0;
    constexpr int LDSB = STAGE_B > TRAN_B ? STAGE_B : TRAN_B;
    __shared__ __align__(16) char ldsraw[LDSB];
    u16* lds = (u16*)ldsraw;

    int q8 = gridDim.x >> 3;
    int wid = (blockIdx.x & 7) * q8 + (blockIdx.x >> 3);
    int xs = wid % NXS; int t0 = wid / NXS;
    int rgrp = t0 % NRG; int n = t0 / NRG;

    int BR = rgrp * (CR * SW);
    int rbase = BR + XOFF;
    int xbase = xs * (MT * 16);

    int tid = threadIdx.x;
    int wv = tid >> 6;
    int lane = tid & 63;
    int l15 = lane & 15, lg = lane >> 4;
    int og = wv % OG, rg = wv / OG;

    f32x4 accP[CR][MT][NTW], accQ[CR][MT][NTW];
#pragma unroll
    for (int cr = 0; cr < CR; ++cr)
#pragma unroll
        for (int m = 0; m < MT; ++m)
#pragma unroll
            for (int nc = 0; nc < NTW; ++nc) {
                accP[cr][m][nc] = f32x4{0.f, 0.f, 0.f, 0.f};
                accQ[cr][m][nc] = f32x4{0.f, 0.f, 0.f, 0.f};
            }

    const u16* wfl = wf + (size_t)lane * 8;
    const u16* actn = act + ((size_t)n * Hp) * Wp * ICIN;

    // single staging pass: logical chunk cg: [0,ICR8)=hi icc, [ICR8,2*ICR8)=lo
    for (int u = tid; u < CHUNKS; u += NW * 64) {
        int c = u & 7; int rest = u >> 3;
        int xl = rest % WT; int row = rest / WT;
        int cg = c ^ (xl & 7);
        int gx = xbase + xl, gr = rbase + row;
        s16x8 v = {0, 0, 0, 0, 0, 0, 0, 0};
        if (cg < 2 * ICR8 && gx < Wp && gr < Hp) {
            int sp = cg < ICR8 ? 0 : 1;
            int icc = cg < ICR8 ? cg : cg - ICR8;
            v = *(const s16x8*)(actn + (size_t)sp * actLO +
                  ((size_t)gr * Wp + gx) * ICIN + icc * 8);
        }
        *(s16x8*)&lds[(size_t)u * 8] = v;
    }
    __syncthreads();

    constexpr int STEPS = 5 * PASSES;
    auto loadBf = [&](int s, bf16x8 (&bh)[NTW], bf16x8 (&bl)[NTW]) {
        const u16* bp = wfl + ((size_t)s * NT + og * NTW) * 512;
#pragma unroll
        for (int nc = 0; nc < NTW; ++nc) {
            bh[nc] = *(const bf16x8*)(bp + nc * 512);
            bl[nc] = *(const bf16x8*)(bp + nc * 512 + wfLO);
        }
    };
    bf16x8 bhD[2][NTW], blD[2][NTW];
    loadBf(0, bhD[0], blD[0]);
#pragma unroll
    for (int s = 0; s < STEPS; ++s) {
        if (s + 1 < STEPS) loadBf(s + 1, bhD[(s + 1) & 1], blD[(s + 1) & 1]);
        const int ky = s / PASSES, p = s % PASSES;
        int kc2 = p * 4 + lg;
        int kx = kc2 / ICR8;
        int icc = kc2 - kx * ICR8;
        if (kx > 4) { kx = 4; icc = 0; }     // pad chunk: B is zero there
#pragma unroll
        for (int m = 0; m < MT; ++m) {
            int xl = m * 16 + XOFF + l15 + kx;
            int sw = xl & 7;
            bf16x8 ah[CR], al[CR];
#pragma unroll
            for (int cr = 0; cr < CR; ++cr) {
                int row = rg * CR + cr + ky;
                int base = (row * WT + xl) * 8;
                ah[cr] = *(const bf16x8*)&lds[(size_t)(base + (icc ^ sw)) * 8];
                al[cr] = *(const bf16x8*)&lds[(size_t)(base + ((ICR8 + icc) ^ sw)) * 8];
            }
#pragma unroll
            for (int nc = 0; nc < NTW; ++nc)
#pragma unroll
                for (int cr = 0; cr < CR; ++cr) {
                    accP[cr][m][nc] = __builtin_amdgcn_mfma_f32_16x16x32_bf16(
                        ah[cr], bhD[s & 1][nc], accP[cr][m][nc], 0, 0, 0);
                    accQ[cr][m][nc] = __builtin_amdgcn_mfma_f32_16x16x32_bf16(
                        ah[cr], blD[s & 1][nc], accQ[cr][m][nc], 0, 0, 0);
                    accQ[cr][m][nc] = __builtin_amdgcn_mfma_f32_16x16x32_bf16(
                        al[cr], bhD[s & 1][nc], accQ[cr][m][nc], 0, 0, 0);
                }
        }
    }

    if constexpr (TRANS) {
        __syncthreads();
        u32* ldsw = (u32*)ldsraw;
#pragma unroll
        for (int nc = 0; nc < NTW; ++nc) {
            int oc = (og * NTW + nc) * 16 + l15;
            float bv = bias[oc >> 2];
#pragma unroll
            for (int m = 0; m < MT; ++m) {
                if constexpr (POOL) {
                    float c0[4], c1[4];
#pragma unroll
                    for (int j = 0; j < 4; ++j) {
                        c0[j] = accP[0][m][nc][j] + accQ[0][m][nc][j];
                        c1[j] = accP[1][m][nc][j] + accQ[1][m][nc][j];
                    }
#pragma unroll
                    for (int a2 = 0; a2 < 2; ++a2) {
                        float mx = fmaxf(fmaxf(c0[2 * a2], c0[2 * a2 + 1]),
                                         fmaxf(c1[2 * a2], c1[2 * a2 + 1]));
                        float v = fmaxf(mx + bv, 0.f);
                        u16 hb = f2bf(v);
                        u16 lb = f2bf(v - bf2f(hb));
                        int px = m * 8 + lg * 2 + a2;
                        ldsw[(rg * TX + px) * SX + oc] = ((u32)hb << 16) | lb;
                    }
                } else {
#pragma unroll
                    for (int cr = 0; cr < CR; ++cr)
#pragma unroll
                        for (int j = 0; j < 4; ++j) {
                            float v = fmaxf(accP[cr][m][nc][j] + accQ[cr][m][nc][j] + bv, 0.f);
                            u16 hb = f2bf(v);
                            u16 lb = f2bf(v - bf2f(hb));
                            int xloc = m * 16 + lg * 4 + j;
                            ldsw[((rg * CR + cr) * TX + xloc) * SX + oc] =
                                ((u32)hb << 16) | lb;
                        }
                }
            }
        }
        __syncthreads();
        constexpr int CPX = OCO / 8;
        constexpr int TOT = TROWS * TX * 2 * CPX;
        int OHL = POOL ? PH : OH;
        int OWL = POOL ? POW : OW;
        int obr = POOL ? rgrp * SW : BR;
        int obx = POOL ? (xbase >> 1) : xbase;
        for (int u = tid; u < TOT; u += NW * 64) {
            int c = u % CPX; int rest = u / CPX;
            int pl = rest & 1; rest >>= 1;
            int x = rest % TX; int row = rest / TX;
            int gr = obr + row, gx = obx + x;
            if (gr >= OHL || gx >= OWL) continue;
            s16x8 v = {0, 0, 0, 0, 0, 0, 0, 0};
            if (c * 8 < NT * 16) {
                const u32* p = &ldsw[(row * TX + x) * SX + c * 8];
                uint4 w0 = *(const uint4*)p;
                uint4 w1 = *(const uint4*)(p + 4);
                if (pl == 0) {
                    v[0] = (short)(w0.x >> 16); v[1] = (short)(w0.y >> 16);
                    v[2] = (short)(w0.z >> 16); v[3] = (short)(w0.w >> 16);
                    v[4] = (short)(w1.x >> 16); v[5] = (short)(w1.y >> 16);
                    v[6] = (short)(w1.z >> 16); v[7] = (short)(w1.w >> 16);
                } else {
                    v[0] = (short)(w0.x & 0xffff); v[1] = (short)(w0.y & 0xffff);
                    v[2] = (short)(w0.z & 0xffff); v[3] = (short)(w0.w & 0xffff);
                    v[4] = (short)(w1.x & 0xffff); v[5] = (short)(w1.y & 0xffff);
                    v[6] = (short)(w1.z & 0xffff); v[7] = (short)(w1.w & 0xffff);
                }
            }
            *(s16x8*)(outP + (size_t)pl * outLO +
                      (((size_t)n * HpO + gr + 2) * WpO + gx + 2) * OCO + c * 8) = v;
        }
    } else {
#pragma unroll
        for (int nc = 0; nc < NTW; ++nc) {
            int oc = (og * NTW + nc) * 16 + l15;
            float bv = bias[oc >> 2];
#pragma unroll
            for (int m = 0; m < MT; ++m) {
                int gx0 = xbase + m * 16;
#pragma unroll
                for (int cr = 0; cr < CR; ++cr) {
                    int oy = BR + rg * CR + cr;
                    if (oy < OH) {
#pragma unroll
                        for (int j = 0; j < 4; ++j) {
                            int gx = gx0 + lg * 4 + j;
                            if (gx < OW) {
                                float v = fmaxf(accP[cr][m][nc][j] + accQ[cr][m][nc][j] + bv, 0.f);
                                outF[(((size_t)n * OH + oy) * OW + gx) * (NT * 16) + oc] = v;
                            }
                        }
                    }
                }
            }
        }
    }
}

// ---------------------------------------------------------------------------
// Windowed MFMA conv (conv2..5), unchanged from r13.
// ---------------------------------------------------------------------------
template <int IC32, int ICIN, int NT, int NTW, int MT, int CR, int SW, bool POOL,
          int XOFF, int OCO, bool TRANS, int PMODE>
__global__ __launch_bounds__(SW*(NT/NTW)*64, 2) void conv_mfma_kernel(
        const u16* __restrict__ act, long actLO,
        const u16* __restrict__ wf, int wfLO,
        const float* __restrict__ bias,
        u16* __restrict__ outP, long outLO,
        float* __restrict__ outF,
        int Hp, int Wp, int OH, int OW, int PH, int POW,
        int NRG, int NXS, int HpO, int WpO) {
    constexpr int OG = NT / NTW;
    constexpr int NW = SW * OG;
    constexpr int KC = IC32 / 32;
    constexpr int WT = MT * 16 + 4 + XOFF;
    constexpr int R  = CR * SW + 4;
    constexpr int CHUNKS = R * WT * 8;
    constexpr int TROWS = POOL ? SW : CR * SW;
    constexpr int TX = POOL ? MT * 8 : MT * 16;
    constexpr int SX = OCO + 4;
    constexpr int STAGE_B = CHUNKS * 16;
    constexpr int TRAN_B = TRANS ? TROWS * TX * SX * 4 : 0;
    constexpr int LDSB = STAGE_B > TRAN_B ? STAGE_B : TRAN_B;
    __shared__ __align__(16) char ldsraw[LDSB];
    u16* lds = (u16*)ldsraw;

    int q8 = gridDim.x >> 3;
    int wid = (blockIdx.x & 7) * q8 + (blockIdx.x >> 3);
    int xs = wid % NXS; int t0 = wid / NXS;
    int rgrp = t0 % NRG; int n = t0 / NRG;

    int BR = rgrp * (CR * SW);
    int rbase = BR + XOFF;
    int xbase = xs * (MT * 16);

    int tid = threadIdx.x;
    int wv = tid >> 6;
    int lane = tid & 63;
    int l15 = lane & 15, lg = lane >> 4;
    int og = wv % OG, rg = wv / OG;

    f32x4 accP[CR][MT][NTW], accQ[CR][MT][NTW];
#pragma unroll
    for (int cr = 0; cr < CR; ++cr)
#pragma unroll
        for (int m = 0; m < MT; ++m)
#pragma unroll
            for (int nc = 0; nc < NTW; ++nc) {
                accP[cr][m][nc] = f32x4{0.f, 0.f, 0.f, 0.f};
                accQ[cr][m][nc] = f32x4{0.f, 0.f, 0.f, 0.f};
            }

    const u16* wfl = wf + (size_t)lane * 8;
    const u16* actn = act + ((size_t)n * Hp) * Wp * ICIN;

    for (int kcp = 0; kcp < KC; ++kcp) {
        if (kcp) __syncthreads();
        for (int u = tid; u < CHUNKS; u += NW * 64) {
            int c = u & 7; int rest = u >> 3;
            int xl = rest % WT; int row = rest / WT;
            int cg = c ^ (xl & 7);
            int sp = cg >> 2, cc4 = cg & 3;
            int gx = xbase + xl, gr = rbase + row;
            int ch0 = (kcp * 4 + cc4) * 8;
            s16x8 v = {0, 0, 0, 0, 0, 0, 0, 0};
            if (gx < Wp && gr < Hp && ch0 < ICIN)
                v = *(const s16x8*)(actn + (size_t)sp * actLO +
                      ((size_t)gr * Wp + gx) * ICIN + ch0);
            *(s16x8*)&lds[(size_t)u * 8] = v;
        }
        __syncthreads();

        auto loadB = [&](int w, bf16x8 (&bh)[NTW], bf16x8 (&bl)[NTW]) {
            const u16* bp = wfl + ((size_t)(w * KC + kcp) * NT + og * NTW) * 512;
#pragma unroll
            for (int nc = 0; nc < NTW; ++nc) {
                bh[nc] = *(const bf16x8*)(bp + nc * 512);
                bl[nc] = *(const bf16x8*)(bp + nc * 512 + wfLO);
            }
        };

        if constexpr (PMODE == 1) {
            auto loadA = [&](int w, bf16x8 (&ah)[MT][CR], bf16x8 (&al)[MT][CR]) {
                int wky = w / 5, wkx = w - wky * 5;
#pragma unroll
                for (int m = 0; m < MT; ++m) {
                    int xl = m * 16 + XOFF + l15 + wkx;
                    int sw = xl & 7;
#pragma unroll
                    for (int cr = 0; cr < CR; ++cr) {
                        int row = rg * CR + cr + wky;
                        int base = (row * WT + xl) * 8;
                        ah[m][cr] = *(const bf16x8*)&lds[(size_t)(base + (lg ^ sw)) * 8];
                        al[m][cr] = *(const bf16x8*)&lds[(size_t)(base + ((4 + lg) ^ sw)) * 8];
                    }
                }
            };
            auto mfmaBlk = [&](bf16x8 (&bh)[NTW], bf16x8 (&bl)[NTW],
                               bf16x8 (&ah)[MT][CR], bf16x8 (&al)[MT][CR]) {
#pragma unroll
                for (int m = 0; m < MT; ++m)
#pragma unroll
                    for (int nc = 0; nc < NTW; ++nc)
#pragma unroll
                        for (int cr = 0; cr < CR; ++cr) {
                            accP[cr][m][nc] = __builtin_amdgcn_mfma_f32_16x16x32_bf16(
                                ah[m][cr], bh[nc], accP[cr][m][nc], 0, 0, 0);
                            accQ[cr][m][nc] = __builtin_amdgcn_mfma_f32_16x16x32_bf16(
                                ah[m][cr], bl[nc], accQ[cr][m][nc], 0, 0, 0);
                            accQ[cr][m][nc] = __builtin_amdgcn_mfma_f32_16x16x32_bf16(
                                al[m][cr], bh[nc], accQ[cr][m][nc], 0, 0, 0);
                        }
            };
            bf16x8 bhX[NTW], blX[NTW], ahX[MT][CR], alX[MT][CR];
            bf16x8 bhY[NTW], blY[NTW], ahY[MT][CR], alY[MT][CR];
            loadB(0, bhX, blX); loadA(0, ahX, alX);
            for (int t = 0; t < 12; ++t) {
                loadB(2 * t + 1, bhY, blY); loadA(2 * t + 1, ahY, alY);
                mfmaBlk(bhX, blX, ahX, alX);
                loadB(2 * t + 2, bhX, blX); loadA(2 * t + 2, ahX, alX);
                mfmaBlk(bhY, blY, ahY, alY);
            }
            mfmaBlk(bhX, blX, ahX, alX);
        } else {
            auto window = [&](int w, bf16x8 (&bh)[NTW], bf16x8 (&bl)[NTW]) {
                int wky = w / 5, wkx = w - wky * 5;
#pragma unroll
                for (int m = 0; m < MT; ++m) {
                    int xl = m * 16 + XOFF + l15 + wkx;
                    int sw = xl & 7;
                    bf16x8 ah[CR], al[CR];
#pragma unroll
                    for (int cr = 0; cr < CR; ++cr) {
                        int row = rg * CR + cr + wky;
                        int base = (row * WT + xl) * 8;
                        ah[cr] = *(const bf16x8*)&lds[(size_t)(base + (lg ^ sw)) * 8];
                        al[cr] = *(const bf16x8*)&lds[(size_t)(base + ((4 + lg) ^ sw)) * 8];
                    }
#pragma unroll
                    for (int nc = 0; nc < NTW; ++nc)
#pragma unroll
                        for (int cr = 0; cr < CR; ++cr) {
                            accP[cr][m][nc] = __builtin_amdgcn_mfma_f32_16x16x32_bf16(
                                ah[cr], bh[nc], accP[cr][m][nc], 0, 0, 0);
                            accQ[cr][m][nc] = __builtin_amdgcn_mfma_f32_16x16x32_bf16(
                                ah[cr], bl[nc], accQ[cr][m][nc], 0, 0, 0);
                            accQ[cr][m][nc] = __builtin_amdgcn_mfma_f32_16x16x32_bf16(
                                al[cr], bh[nc], accQ[cr][m][nc], 0, 0, 0);
                        }
                }
            };
            bf16x8 bhX[NTW], blX[NTW], bhY[NTW], blY[NTW];
            loadB(0, bhX, blX);
            for (int t = 0; t < 12; ++t) {
                loadB(2 * t + 1, bhY, blY);
                window(2 * t, bhX, blX);
                loadB(2 * t + 2, bhX, blX);
                window(2 * t + 1, bhY, blY);
            }
            window(24, bhX, blX);
        }
    }

    if constexpr (TRANS) {
        __syncthreads();
        u32* ldsw = (u32*)ldsraw;
#pragma unroll
        for (int nc = 0; nc < NTW; ++nc) {
            int oc = (og * NTW + nc) * 16 + l15;
            float bv = bias[oc >> 2];
#pragma unroll
            for (int m = 0; m < MT; ++m) {
                if constexpr (POOL) {
                    float c0[4], c1[4];
#pragma unroll
                    for (int j = 0; j < 4; ++j) {
                        c0[j] = accP[0][m][nc][j] + accQ[0][m][nc][j];
                        c1[j] = accP[1][m][nc][j] + accQ[1][m][nc][j];
                    }
#pragma unroll
                    for (int a2 = 0; a2 < 2; ++a2) {
                        float mx = fmaxf(fmaxf(c0[2 * a2], c0[2 * a2 + 1]),
                                         fmaxf(c1[2 * a2], c1[2 * a2 + 1]));
                        float v = fmaxf(mx + bv, 0.f);
                        u16 hb = f2bf(v);
                        u16 lb = f2bf(v - bf2f(hb));
                        int px = m * 8 + lg * 2 + a2;
                        ldsw[(rg * TX + px) * SX + oc] = ((u32)hb << 16) | lb;
                    }
                } else {
#pragma unroll
                    for (int cr = 0; cr < CR; ++cr)
#pragma unroll
                        for (int j = 0; j < 4; ++j) {
                            float v = fmaxf(accP[cr][m][nc][j] + accQ[cr][m][nc][j] + bv, 0.f);
                            u16 hb = f2bf(v);
                            u16 lb = f2bf(v - bf2f(hb));
                            int xloc = m * 16 + lg * 4 + j;
                            ldsw[((rg * CR + cr) * TX + xloc) * SX + oc] =
                                ((u32)hb << 16) | lb;
                        }
                }
            }
        }
        __syncthreads();
        constexpr int CPX = OCO / 8;
        constexpr int TOT = TROWS * TX * 2 * CPX;
        int OHL = POOL ? PH : OH;
        int OWL = POOL ? POW : OW;
        int obr = POOL ? rgrp * SW : BR;
        int obx = POOL ? (xbase >> 1) : xbase;
        for (int u = tid; u < TOT; u += NW * 64) {
            int c = u % CPX; int rest = u / CPX;
            int pl = rest & 1; rest >>= 1;
            int x = rest % TX; int row = rest / TX;
            int gr = obr + row, gx = obx + x;
            if (gr >= OHL || gx >= OWL) continue;
            s16x8 v = {0, 0, 0, 0, 0, 0, 0, 0};
            if (c * 8 < NT * 16) {
                const u32* p = &ldsw[(row * TX + x) * SX + c * 8];
                uint4 w0 = *(const uint4*)p;
                uint4 w1 = *(const uint4*)(p + 4);
                if (pl == 0) {
                    v[0] = (short)(w0.x >> 16); v[1] = (short)(w0.y >> 16);
                    v[2] = (short)(w0.z >> 16); v[3] = (short)(w0.w >> 16);
                    v[4] = (short)(w1.x >> 16); v[5] = (short)(w1.y >> 16);
                    v[6] = (short)(w1.z >> 16); v[7] = (short)(w1.w >> 16);
                } else {
                    v[0] = (short)(w0.x & 0xffff); v[1] = (short)(w0.y & 0xffff);
                    v[2] = (short)(w0.z & 0xffff); v[3] = (short)(w0.w & 0xffff);
                    v[4] = (short)(w1.x & 0xffff); v[5] = (short)(w1.y & 0xffff);
                    v[6] = (short)(w1.z & 0xffff); v[7] = (short)(w1.w & 0xffff);
                }
            }
            *(s16x8*)(outP + (size_t)pl * outLO +
                      (((size_t)n * HpO + gr + 2) * WpO + gx + 2) * OCO + c * 8) = v;
        }
    } else {
#pragma unroll
        for (int nc = 0; nc < NTW; ++nc) {
            int oc = (og * NTW + nc) * 16 + l15;
            float bv = bias[oc >> 2];
#pragma unroll
            for (int m = 0; m < MT; ++m) {
                int gx0 = xbase + m * 16;
#pragma unroll
                for (int cr = 0; cr < CR; ++cr) {
                    int oy = BR + rg * CR + cr;
                    if (oy < OH) {
#pragma unroll
                        for (int j = 0; j < 4; ++j) {
                            int gx = gx0 + lg * 4 + j;
                            if (gx < OW) {
                                float v = fmaxf(accP[cr][m][nc][j] + accQ[cr][m][nc][j] + bv, 0.f);
                                outF[(((size_t)n * OH + oy) * OW + gx) * (NT * 16) + oc] = v;
                            }
                        }
                    }
                }
            }
        }
    }
}

// mean over 21x21 spatial of NHWC fp32 [64][21][21][64] -> (64,64)
__global__ void mean_nhwc_kernel(const float* __restrict__ in, float* __restrict__ out) {
    __shared__ float sm[256];
    int n = blockIdx.x;
    int c = threadIdx.x & 63, q = threadIdx.x >> 6;
    float s = 0.f;
    for (int p = q; p < 441; p += 4) s += in[((size_t)n * 441 + p) * 64 + c];
    sm[threadIdx.x] = s;
    __syncthreads();
    if (q == 0) out[n * 64 + c] = (sm[c] + sm[c + 64] + sm[c + 128] + sm[c + 192]) * (1.0f / 441.0f);
}

// single block: fc1 (64x64, relu) then fc2 (10x64)
__global__ void fc_kernel(const float* __restrict__ mean, const float* __restrict__ fw1,
                          const float* __restrict__ fb1, const float* __restrict__ fw2,
                          const float* __restrict__ fb2, float* __restrict__ out) {
    __shared__ float m[4096];
    __shared__ float h1[4096];
    int tid = threadIdx.x;
    for (int i = tid; i < 4096; i += 256) m[i] = mean[i];
    __syncthreads();
    for (int i = tid; i < 4096; i += 256) {
        int n = i >> 6, j = i & 63;
        float s = fb1[j];
        for (int k = 0; k < 64; ++k) s = fmaf(m[n * 64 + k], fw1[j * 64 + k], s);
        h1[i] = fmaxf(s, 0.f);
    }
    __syncthreads();
    for (int i = tid; i < 640; i += 256) {
        int n = i / 10, j2 = i % 10;
        float s = fb2[j2];
        for (int j = 0; j < 64; ++j) s = fmaf(h1[n * 64 + j], fw2[j2 * 64 + j], s);
        out[i] = s;
    }
}

extern "C" void kernel_launch(void* const* d_in, const int* in_sizes, int n_in,
                              void* d_out, int out_size, void* d_ws, size_t ws_size,
                              hipStream_t stream) {
    const float* x   = (const float*)d_in[0];
    const float* w0  = (const float*)d_in[1];
    const float* b0  = (const float*)d_in[2];
    const float* w1  = (const float*)d_in[3];
    const float* b1  = (const float*)d_in[4];
    const float* w2  = (const float*)d_in[5];
    const float* b2  = (const float*)d_in[6];
    const float* w3  = (const float*)d_in[7];
    const float* b3  = (const float*)d_in[8];
    const float* w4  = (const float*)d_in[9];
    const float* b4  = (const float*)d_in[10];
    const float* w5  = (const float*)d_in[11];
    const float* b5  = (const float*)d_in[12];
    const float* fw1 = (const float*)d_in[13];
    const float* fb1 = (const float*)d_in[14];
    const float* fw2 = (const float*)d_in[15];
    const float* fb2 = (const float*)d_in[16];

    char* ws = (char*)d_ws;
    if (ws_size < 128827392ull) return;

    float* F0   = (float*)(ws + 0);
    u16*   WF1  = (u16*)(ws + 8192);
    u16*   WF2  = (u16*)(ws + 161792);
    u16*   WF3  = (u16*)(ws + 468992);
    u16*   WF4  = (u16*)(ws + 1083392);
    u16*   WF5  = (u16*)(ws + 2004992);
    float* MEANB= (float*)(ws + 2619392);
    float* XP   = (float*)(ws + 2635776);
    float* C5   = (float*)(ws + 5144576);
    u16*   A    = (u16*)(ws + 12369920);    // P1 / P3 / P5
    u16*   B    = (u16*)(ws + 87867392);    // P2 / P4
    const long P1LO = 14155776;   // 64*96*96*24
    const long P2LO = 10240000;   // 64*50*50*64
    const long P4LO = 4478976;    // 64*27*27*96

    // --- weight transforms ---
    hipLaunchKernelGGL(lift_w0T_kernel, dim3(5), dim3(256), 0, stream, w0, F0);
    // conv1 folded fragments: 5 ky x 4 passes x NT3 -> 30720 elems/plane
    hipLaunchKernelGGL(wfrag_fold_kernel, dim3(120), dim3(256), 0, stream,
                       w1, WF1, 12, 6, 4, 3, 3, 30720);
    hipLaunchKernelGGL(wfrag_kernel, dim3(300), dim3(256), 0, stream, w2, WF2, 12, 12, 2, 3, 76800);
    hipLaunchKernelGGL(wfrag_kernel, dim3(600), dim3(256), 0, stream, w3, WF3, 24, 12, 2, 6, 153600);
    hipLaunchKernelGGL(wfrag_kernel, dim3(900), dim3(256), 0, stream, w4, WF4, 24, 24, 3, 6, 230400);
    hipLaunchKernelGGL(wfrag_kernel, dim3(600), dim3(256), 0, stream, w5, WF5, 16, 24, 3, 4, 153600);

    // --- input pad (fp32) ---
    hipMemsetAsync(XP, 0, 2508800, stream);
    hipLaunchKernelGGL(pad_x_kernel, dim3(2304), dim3(256), 0, stream, x, XP);

    // --- P1 halo prep + conv0 (P1: [96][96][24]) ---
    hipLaunchKernelGGL(prep_halo_kernel, dim3(2304), dim3(256), 0, stream,
                       A, P1LO, 64*96*96, 96, 96, 24);
    hipLaunchKernelGGL(conv0_kernel, dim3((64*92*23 + 255)/256), dim3(256), 0, stream,
                       XP, F0, b0, A, P1LO);

    // --- P2 halo prep + conv1 (+pool): P1 -> P2 [50][50][64] --- K-FOLD
    hipLaunchKernelGGL(prep_halo_kernel, dim3(625), dim3(256), 0, stream,
                       B, P2LO, 64*50*50, 50, 50, 64);
    hipLaunchKernelGGL((conv_fold_kernel<3, 24, 4, 3, 3, 3, 2, 4, true, 0, 64, true>),
                       dim3(1536), dim3(256), 0, stream,
                       A, P1LO, WF1, 30720, b1, B, P2LO, (float*)nullptr,
                       96, 96, 92, 92, 46, 46, 12, 2, 50, 50);

    // --- P3 halo prep + conv2: P2 -> P3 (A) [50][50][64] --- PMODE 1
    hipLaunchKernelGGL(prep_halo_kernel, dim3(625), dim3(256), 0, stream,
                       A, P2LO, 64*50*50, 50, 50, 64);
    hipLaunchKernelGGL((conv_mfma_kernel<64, 64, 3, 3, 3, 1, 4, false, 0, 64, true, 1>),
                       dim3(768), dim3(256), 0, stream,
                       B, P2LO, WF2, 76800, b2, A, P2LO, (float*)nullptr,
                       50, 50, 46, 46, 0, 0, 12, 1, 50, 50);

    // --- P4 halo prep + conv3 (+pool): P3 -> P4 (B) [27][27][96] --- PMODE 0
    hipLaunchKernelGGL(prep_halo_kernel, dim3(183), dim3(256), 0, stream,
                       B, P4LO, 64*27*27, 27, 27, 96);
    hipLaunchKernelGGL((conv_mfma_kernel<64, 64, 6, 3, 3, 2, 2, true, 0, 96, true, 0>),
                       dim3(768), dim3(256), 0, stream,
                       A, P2LO, WF3, 153600, b3, B, P4LO, (float*)nullptr,
                       50, 50, 46, 46, 23, 23, 12, 1, 27, 27);

    // --- P5 halo prep + conv4: P4 -> P5 (A) [27][27][96] --- PMODE 1
    hipLaunchKernelGGL(prep_halo_kernel, dim3(183), dim3(256), 0, stream,
                       A, P4LO, 64*27*27, 27, 27, 96);
    hipLaunchKernelGGL((conv_mfma_kernel<96, 96, 6, 3, 2, 2, 2, false, 0, 96, true, 1>),
                       dim3(384), dim3(256), 0, stream,
                       B, P4LO, WF4, 230400, b4, A, P4LO, (float*)nullptr,
                       27, 27, 23, 23, 0, 0, 6, 1, 27, 27);

    // --- conv5: P5 -> C5 fp32 NHWC compact [21][21][64] --- PMODE 1
    hipLaunchKernelGGL((conv_mfma_kernel<96, 96, 4, 2, 2, 2, 2, false, 1, 96, false, 1>),
                       dim3(384), dim3(256), 0, stream,
                       A, P4LO, WF5, 153600, b5, (u16*)A, 0, C5,
                       27, 27, 21, 21, 0, 0, 6, 1, 27, 27);

    // --- mean + fc ---
    hipLaunchKernelGGL(mean_nhwc_kernel, dim3(64), dim3(256), 0, stream, C5, MEANB);
    hipLaunchKernelGGL(fc_kernel, dim3(1), dim3(256), 0, stream,
                       MEANB, fw1, fb1, fw2, fb2, (float*)d_out);
}

// Round 15
// 571.874 us; speedup vs baseline: 1.2732x; 1.2732x over previous
//
#include <hip/hip_runtime.h>
#include <hip/hip_bf16.h>

// ---------------------------------------------------------------------------
// C4 equivariant CNN, round 15: revert to r13 (verified best, 571.8 us).
//  r14's K-fold regressed (spill: WRITE 768MB; LDS conflicts 1.5M) — the
//  full unroll + lane-dependent fold addressing broke both the register
//  budget and the conflict-free chunk partition. This is the r13 config:
//  - conv1..5: MFMA implicit-GEMM, split-bf16 (hi/lo), LDS chunk-swizzled
//  - PMODE 1 (full A+B ping-pong) for conv2/4/5; PMODE 0 (B-only ping-pong,
//    A per-m in-window) for conv1/conv3 whose acc tiles would spill.
//  - LDS-transposed epilogue, P1 24ch, halo-only prep, no forced unroll.
// ---------------------------------------------------------------------------

typedef short s16x8 __attribute__((ext_vector_type(8)));
typedef __bf16 bf16x8 __attribute__((ext_vector_type(8)));
typedef float f32x4 __attribute__((ext_vector_type(4)));
typedef unsigned short u16;
typedef unsigned int u32;

__device__ __forceinline__ u16 f2bf(float f) {      // RNE fp32 -> bf16 bits
    unsigned u = __float_as_uint(f);
    return (u16)((u + 0x7FFFu + ((u >> 16) & 1u)) >> 16);
}
__device__ __forceinline__ float bf2f(u16 h) {
    return __uint_as_float(((unsigned)h) << 16);
}

__device__ __forceinline__ void rot_src(int r, int K, int y, int x, int& sy, int& sx) {
    switch (r & 3) {
        case 0: sy = y;         sx = x;         break;
        case 1: sy = x;         sx = K - 1 - y; break;
        case 2: sy = K - 1 - y; sx = K - 1 - x; break;
        default: sy = K - 1 - x; sx = y;        break;
    }
}

// w0: (6,1,7,7) -> F0T: [49][24] fp32
__global__ void lift_w0T_kernel(const float* __restrict__ w, float* __restrict__ f) {
    const int K = 7, KK = 49, OC = 24;
    int idx = blockIdx.x * blockDim.x + threadIdx.x;
    if (idx >= KK * OC) return;
    int oc = idx % OC; int kk = idx / OC;
    int y = kk / K, x = kk % K;
    int r = oc & 3, o = oc >> 2;
    int sy, sx; rot_src(r, K, y, x, sy, sx);
    f[idx] = w[o * KK + sy * K + sx];
}

// group-transform + split + pack into MFMA B-fragment order.
__global__ void wfrag_kernel(const float* __restrict__ w, u16* __restrict__ wf,
                             int O, int I, int KC, int NT, int total) {
    int idx = blockIdx.x * blockDim.x + threadIdx.x;
    if (idx >= total) return;
    int j = idx & 7;
    int lane = (idx >> 3) & 63;
    int rest = idx >> 9;
    int nc = rest % NT; rest /= NT;
    int kc = rest % KC; int kpos = rest / KC;
    int ky = kpos / 5, kx = kpos % 5;
    int kk = ((lane >> 4) << 3) + j;
    int ic = kc * 32 + kk;
    int oc = nc * 16 + (lane & 15);
    float val = 0.f;
    if (ic < I * 4) {
        int o = oc >> 2, r = oc & 3, i = ic >> 2, s = ic & 3;
        int g = (s - r + 4) & 3;
        int sy, sx; rot_src(r, 5, ky, kx, sy, sx);
        val = w[(((o * I + i) * 4 + g) * 25) + sy * 5 + sx];
    }
    u16 hb = f2bf(val);
    u16 lb = f2bf(val - bf2f(hb));
    wf[idx] = hb;
    wf[idx + total] = lb;
}

// x (64,1,96,96) -> xp (64, 98, 100) fp32 with 1-border (pre-zeroed)
__global__ void pad_x_kernel(const float* __restrict__ x, float* __restrict__ xp) {
    int idx = blockIdx.x * blockDim.x + threadIdx.x;
    if (idx >= 64 * 96 * 96) return;
    int c = idx % 96; int t = idx / 96;
    int r = t % 96; int n = t / 96;
    xp[((size_t)n * 98 + r + 1) * 100 + c + 1] = x[idx];
}

// zero the 2-thick halo border only (both planes); interior written by convs
__global__ void prep_halo_kernel(u16* __restrict__ buf, long LO, int NHW,
                                 int Hp, int Wp, int ICO) {
    int idx = blockIdx.x * blockDim.x + threadIdx.x;
    if (idx >= NHW) return;
    int c = idx % Wp; int t = idx / Wp;
    int r = t % Hp; int n = t / Hp;
    bool halo = (r < 2) || (r >= Hp - 2) || (c < 2) || (c >= Wp - 2);
    if (!halo) return;
    size_t base = (((size_t)n * Hp + r) * Wp + c) * ICO;
    s16x8 z = {0, 0, 0, 0, 0, 0, 0, 0};
    for (int cc = 0; cc < (ICO >> 3); ++cc) {
        *(s16x8*)(buf + base + cc * 8) = z;
        *(s16x8*)(buf + LO + base + cc * 8) = z;
    }
}

// conv0: fp32 direct (IC=1, K=7, pad=1). One thread: ALL 24 oc x 4 x.
// P1: [64][96][96][24] hi|lo, halo 2. Full 48B lines per pixel.
__global__ __launch_bounds__(256) void conv0_kernel(
        const float* __restrict__ xp, const float* __restrict__ f0t,
        const float* __restrict__ b0, u16* __restrict__ p1, long p1LO) {
    int idx = blockIdx.x * blockDim.x + threadIdx.x;
    if (idx >= 64 * 92 * 23) return;
    int xq = idx % 23; int t = idx / 23;
    int oy = t % 92; int n = t / 92;
    float acc[24][4];
#pragma unroll
    for (int a = 0; a < 24; ++a)
#pragma unroll
        for (int b = 0; b < 4; ++b) acc[a][b] = 0.f;

    const float* ip = xp + ((size_t)n * 98 + oy) * 100 + xq * 4;
#pragma unroll
    for (int ky = 0; ky < 7; ++ky) {
        const float* row = ip + (size_t)ky * 100;
        float xv[12];
#pragma unroll
        for (int v = 0; v < 3; ++v)
            *reinterpret_cast<float4*>(&xv[4 * v]) =
                *reinterpret_cast<const float4*>(row + 4 * v);
#pragma unroll
        for (int kx = 0; kx < 7; ++kx) {
            const float* wp = f0t + (ky * 7 + kx) * 24;
#pragma unroll
            for (int qd = 0; qd < 6; ++qd) {
                float4 wv = *reinterpret_cast<const float4*>(wp + qd * 4);
#pragma unroll
                for (int jx = 0; jx < 4; ++jx) {
                    acc[qd * 4 + 0][jx] = fmaf(wv.x, xv[kx + jx], acc[qd * 4 + 0][jx]);
                    acc[qd * 4 + 1][jx] = fmaf(wv.y, xv[kx + jx], acc[qd * 4 + 1][jx]);
                    acc[qd * 4 + 2][jx] = fmaf(wv.z, xv[kx + jx], acc[qd * 4 + 2][jx]);
                    acc[qd * 4 + 3][jx] = fmaf(wv.w, xv[kx + jx], acc[qd * 4 + 3][jx]);
                }
            }
        }
    }
    float bv[6];
#pragma unroll
    for (int qd = 0; qd < 6; ++qd) bv[qd] = b0[qd];

    size_t ob = (((size_t)n * 96 + oy + 2) * 96 + xq * 4 + 2) * 24;
#pragma unroll
    for (int jx = 0; jx < 4; ++jx) {
        s16x8 hv[3], lv[3];
#pragma unroll
        for (int cc = 0; cc < 3; ++cc)
#pragma unroll
            for (int e = 0; e < 8; ++e) {
                int ch = cc * 8 + e;
                float v = fmaxf(acc[ch][jx] + bv[ch >> 2], 0.f);
                u16 hb = f2bf(v);
                u16 lb = f2bf(v - bf2f(hb));
                hv[cc][e] = (short)hb; lv[cc][e] = (short)lb;
            }
#pragma unroll
        for (int cc = 0; cc < 3; ++cc) {
            *(s16x8*)(p1 + ob + jx * 24 + cc * 8) = hv[cc];
            *(s16x8*)(p1 + p1LO + ob + jx * 24 + cc * 8) = lv[cc];
        }
    }
}

// ---------------------------------------------------------------------------
// MFMA conv. wave = MT x-tiles x NTW oc-tiles x CR rows; block = SW row-groups
// x OG oc-groups. KC channel passes (32ch hi+lo staged per pass, swizzled).
// PMODE 1: full A+B ping-pong (fits when acc tile small).
// PMODE 0: B-only ping-pong, A loaded per-m inside window (big acc tiles).
// ---------------------------------------------------------------------------
template <int IC32, int ICIN, int NT, int NTW, int MT, int CR, int SW, bool POOL,
          int XOFF, int OCO, bool TRANS, int PMODE>
__global__ __launch_bounds__(SW*(NT/NTW)*64, 2) void conv_mfma_kernel(
        const u16* __restrict__ act, long actLO,
        const u16* __restrict__ wf, int wfLO,
        const float* __restrict__ bias,
        u16* __restrict__ outP, long outLO,
        float* __restrict__ outF,
        int Hp, int Wp, int OH, int OW, int PH, int POW,
        int NRG, int NXS, int HpO, int WpO) {
    constexpr int OG = NT / NTW;
    constexpr int NW = SW * OG;
    constexpr int KC = IC32 / 32;
    constexpr int WT = MT * 16 + 4 + XOFF;
    constexpr int R  = CR * SW + 4;
    constexpr int CHUNKS = R * WT * 8;          // 16B chunks per pass (hi+lo)
    constexpr int TROWS = POOL ? SW : CR * SW;  // output rows per block
    constexpr int TX = POOL ? MT * 8 : MT * 16; // output x per block
    constexpr int SX = OCO + 4;                 // u32 stride per x (+16B pad)
    constexpr int STAGE_B = CHUNKS * 16;
    constexpr int TRAN_B = TRANS ? TROWS * TX * SX * 4 : 0;
    constexpr int LDSB = STAGE_B > TRAN_B ? STAGE_B : TRAN_B;
    __shared__ __align__(16) char ldsraw[LDSB];
    u16* lds = (u16*)ldsraw;

    // bijective XCD swizzle (grid always a multiple of 8)
    int q8 = gridDim.x >> 3;
    int wid = (blockIdx.x & 7) * q8 + (blockIdx.x >> 3);
    int xs = wid % NXS; int t0 = wid / NXS;
    int rgrp = t0 % NRG; int n = t0 / NRG;

    int BR = rgrp * (CR * SW);      // conv-row base of block
    int rbase = BR + XOFF;          // input row base
    int xbase = xs * (MT * 16);     // conv-x base

    int tid = threadIdx.x;
    int wv = tid >> 6;
    int lane = tid & 63;
    int l15 = lane & 15, lg = lane >> 4;
    int og = wv % OG, rg = wv / OG;

    f32x4 accP[CR][MT][NTW], accQ[CR][MT][NTW];
#pragma unroll
    for (int cr = 0; cr < CR; ++cr)
#pragma unroll
        for (int m = 0; m < MT; ++m)
#pragma unroll
            for (int nc = 0; nc < NTW; ++nc) {
                accP[cr][m][nc] = f32x4{0.f, 0.f, 0.f, 0.f};
                accQ[cr][m][nc] = f32x4{0.f, 0.f, 0.f, 0.f};
            }

    const u16* wfl = wf + (size_t)lane * 8;
    const u16* actn = act + ((size_t)n * Hp) * Wp * ICIN;

    for (int kcp = 0; kcp < KC; ++kcp) {
        if (kcp) __syncthreads();
        // stage channels 32*kcp..+31, both planes, chunk-swizzled; chunks
        // beyond ICIN are zero-filled here (P1 stores only 24 real channels)
        for (int u = tid; u < CHUNKS; u += NW * 64) {
            int c = u & 7; int rest = u >> 3;
            int xl = rest % WT; int row = rest / WT;
            int cg = c ^ (xl & 7);
            int sp = cg >> 2, cc4 = cg & 3;
            int gx = xbase + xl, gr = rbase + row;
            int ch0 = (kcp * 4 + cc4) * 8;
            s16x8 v = {0, 0, 0, 0, 0, 0, 0, 0};
            if (gx < Wp && gr < Hp && ch0 < ICIN)
                v = *(const s16x8*)(actn + (size_t)sp * actLO +
                      ((size_t)gr * Wp + gx) * ICIN + ch0);
            *(s16x8*)&lds[(size_t)u * 8] = v;
        }
        __syncthreads();

        auto loadB = [&](int w, bf16x8 (&bh)[NTW], bf16x8 (&bl)[NTW]) {
            const u16* bp = wfl + ((size_t)(w * KC + kcp) * NT + og * NTW) * 512;
#pragma unroll
            for (int nc = 0; nc < NTW; ++nc) {
                bh[nc] = *(const bf16x8*)(bp + nc * 512);
                bl[nc] = *(const bf16x8*)(bp + nc * 512 + wfLO);
            }
        };

        if constexpr (PMODE == 1) {
            // ---- full A+B ping-pong (register budget permits) ----
            auto loadA = [&](int w, bf16x8 (&ah)[MT][CR], bf16x8 (&al)[MT][CR]) {
                int wky = w / 5, wkx = w - wky * 5;
#pragma unroll
                for (int m = 0; m < MT; ++m) {
                    int xl = m * 16 + XOFF + l15 + wkx;
                    int sw = xl & 7;
#pragma unroll
                    for (int cr = 0; cr < CR; ++cr) {
                        int row = rg * CR + cr + wky;
                        int base = (row * WT + xl) * 8;
                        ah[m][cr] = *(const bf16x8*)&lds[(size_t)(base + (lg ^ sw)) * 8];
                        al[m][cr] = *(const bf16x8*)&lds[(size_t)(base + ((4 + lg) ^ sw)) * 8];
                    }
                }
            };
            auto mfmaBlk = [&](bf16x8 (&bh)[NTW], bf16x8 (&bl)[NTW],
                               bf16x8 (&ah)[MT][CR], bf16x8 (&al)[MT][CR]) {
#pragma unroll
                for (int m = 0; m < MT; ++m)
#pragma unroll
                    for (int nc = 0; nc < NTW; ++nc)
#pragma unroll
                        for (int cr = 0; cr < CR; ++cr) {
                            accP[cr][m][nc] = __builtin_amdgcn_mfma_f32_16x16x32_bf16(
                                ah[m][cr], bh[nc], accP[cr][m][nc], 0, 0, 0);
                            accQ[cr][m][nc] = __builtin_amdgcn_mfma_f32_16x16x32_bf16(
                                ah[m][cr], bl[nc], accQ[cr][m][nc], 0, 0, 0);
                            accQ[cr][m][nc] = __builtin_amdgcn_mfma_f32_16x16x32_bf16(
                                al[m][cr], bh[nc], accQ[cr][m][nc], 0, 0, 0);
                        }
            };
            bf16x8 bhX[NTW], blX[NTW], ahX[MT][CR], alX[MT][CR];
            bf16x8 bhY[NTW], blY[NTW], ahY[MT][CR], alY[MT][CR];
            loadB(0, bhX, blX); loadA(0, ahX, alX);
            for (int t = 0; t < 12; ++t) {
                loadB(2 * t + 1, bhY, blY); loadA(2 * t + 1, ahY, alY);
                mfmaBlk(bhX, blX, ahX, alX);
                loadB(2 * t + 2, bhX, blX); loadA(2 * t + 2, ahX, alX);
                mfmaBlk(bhY, blY, ahY, alY);
            }
            mfmaBlk(bhX, blX, ahX, alX);
        } else {
            // ---- B-only ping-pong; A per-m inside window (no spill) ----
            auto window = [&](int w, bf16x8 (&bh)[NTW], bf16x8 (&bl)[NTW]) {
                int wky = w / 5, wkx = w - wky * 5;
#pragma unroll
                for (int m = 0; m < MT; ++m) {
                    int xl = m * 16 + XOFF + l15 + wkx;
                    int sw = xl & 7;
                    bf16x8 ah[CR], al[CR];
#pragma unroll
                    for (int cr = 0; cr < CR; ++cr) {
                        int row = rg * CR + cr + wky;
                        int base = (row * WT + xl) * 8;
                        ah[cr] = *(const bf16x8*)&lds[(size_t)(base + (lg ^ sw)) * 8];
                        al[cr] = *(const bf16x8*)&lds[(size_t)(base + ((4 + lg) ^ sw)) * 8];
                    }
#pragma unroll
                    for (int nc = 0; nc < NTW; ++nc)
#pragma unroll
                        for (int cr = 0; cr < CR; ++cr) {
                            accP[cr][m][nc] = __builtin_amdgcn_mfma_f32_16x16x32_bf16(
                                ah[cr], bh[nc], accP[cr][m][nc], 0, 0, 0);
                            accQ[cr][m][nc] = __builtin_amdgcn_mfma_f32_16x16x32_bf16(
                                ah[cr], bl[nc], accQ[cr][m][nc], 0, 0, 0);
                            accQ[cr][m][nc] = __builtin_amdgcn_mfma_f32_16x16x32_bf16(
                                al[cr], bh[nc], accQ[cr][m][nc], 0, 0, 0);
                        }
                }
            };
            bf16x8 bhX[NTW], blX[NTW], bhY[NTW], blY[NTW];
            loadB(0, bhX, blX);
            for (int t = 0; t < 12; ++t) {
                loadB(2 * t + 1, bhY, blY);
                window(2 * t, bhX, blX);
                loadB(2 * t + 2, bhX, blX);
                window(2 * t + 1, bhY, blY);
            }
            window(24, bhX, blX);
        }
    }

    if constexpr (TRANS) {
        // ---- transposed epilogue: acc -> LDS u32(hi|lo) -> full-line stores
        __syncthreads();
        u32* ldsw = (u32*)ldsraw;
#pragma unroll
        for (int nc = 0; nc < NTW; ++nc) {
            int oc = (og * NTW + nc) * 16 + l15;
            float bv = bias[oc >> 2];
#pragma unroll
            for (int m = 0; m < MT; ++m) {
                if constexpr (POOL) {
                    float c0[4], c1[4];
#pragma unroll
                    for (int j = 0; j < 4; ++j) {
                        c0[j] = accP[0][m][nc][j] + accQ[0][m][nc][j];
                        c1[j] = accP[1][m][nc][j] + accQ[1][m][nc][j];
                    }
#pragma unroll
                    for (int a2 = 0; a2 < 2; ++a2) {
                        float mx = fmaxf(fmaxf(c0[2 * a2], c0[2 * a2 + 1]),
                                         fmaxf(c1[2 * a2], c1[2 * a2 + 1]));
                        float v = fmaxf(mx + bv, 0.f);
                        u16 hb = f2bf(v);
                        u16 lb = f2bf(v - bf2f(hb));
                        int px = m * 8 + lg * 2 + a2;
                        ldsw[(rg * TX + px) * SX + oc] = ((u32)hb << 16) | lb;
                    }
                } else {
#pragma unroll
                    for (int cr = 0; cr < CR; ++cr)
#pragma unroll
                        for (int j = 0; j < 4; ++j) {
                            float v = fmaxf(accP[cr][m][nc][j] + accQ[cr][m][nc][j] + bv, 0.f);
                            u16 hb = f2bf(v);
                            u16 lb = f2bf(v - bf2f(hb));
                            int xloc = m * 16 + lg * 4 + j;
                            ldsw[((rg * CR + cr) * TX + xloc) * SX + oc] =
                                ((u32)hb << 16) | lb;
                        }
                }
            }
        }
        __syncthreads();
        constexpr int CPX = OCO / 8;               // chunks per pixel per plane
        constexpr int TOT = TROWS * TX * 2 * CPX;
        int OHL = POOL ? PH : OH;
        int OWL = POOL ? POW : OW;
        int obr = POOL ? rgrp * SW : BR;
        int obx = POOL ? (xbase >> 1) : xbase;
        for (int u = tid; u < TOT; u += NW * 64) {
            int c = u % CPX; int rest = u / CPX;
            int pl = rest & 1; rest >>= 1;
            int x = rest % TX; int row = rest / TX;
            int gr = obr + row, gx = obx + x;
            if (gr >= OHL || gx >= OWL) continue;
            s16x8 v = {0, 0, 0, 0, 0, 0, 0, 0};
            if (c * 8 < NT * 16) {
                const u32* p = &ldsw[(row * TX + x) * SX + c * 8];
                uint4 w0 = *(const uint4*)p;
                uint4 w1 = *(const uint4*)(p + 4);
                if (pl == 0) {
                    v[0] = (short)(w0.x >> 16); v[1] = (short)(w0.y >> 16);
                    v[2] = (short)(w0.z >> 16); v[3] = (short)(w0.w >> 16);
                    v[4] = (short)(w1.x >> 16); v[5] = (short)(w1.y >> 16);
                    v[6] = (short)(w1.z >> 16); v[7] = (short)(w1.w >> 16);
                } else {
                    v[0] = (short)(w0.x & 0xffff); v[1] = (short)(w0.y & 0xffff);
                    v[2] = (short)(w0.z & 0xffff); v[3] = (short)(w0.w & 0xffff);
                    v[4] = (short)(w1.x & 0xffff); v[5] = (short)(w1.y & 0xffff);
                    v[6] = (short)(w1.z & 0xffff); v[7] = (short)(w1.w & 0xffff);
                }
            }
            *(s16x8*)(outP + (size_t)pl * outLO +
                      (((size_t)n * HpO + gr + 2) * WpO + gx + 2) * OCO + c * 8) = v;
        }
    } else {
        // ---- direct fp32 epilogue (conv5 -> compact NHWC for mean) ----
#pragma unroll
        for (int nc = 0; nc < NTW; ++nc) {
            int oc = (og * NTW + nc) * 16 + l15;
            float bv = bias[oc >> 2];
#pragma unroll
            for (int m = 0; m < MT; ++m) {
                int gx0 = xbase + m * 16;
#pragma unroll
                for (int cr = 0; cr < CR; ++cr) {
                    int oy = BR + rg * CR + cr;
                    if (oy < OH) {
#pragma unroll
                        for (int j = 0; j < 4; ++j) {
                            int gx = gx0 + lg * 4 + j;
                            if (gx < OW) {
                                float v = fmaxf(accP[cr][m][nc][j] + accQ[cr][m][nc][j] + bv, 0.f);
                                outF[(((size_t)n * OH + oy) * OW + gx) * (NT * 16) + oc] = v;
                            }
                        }
                    }
                }
            }
        }
    }
}

// mean over 21x21 spatial of NHWC fp32 [64][21][21][64] -> (64,64)
__global__ void mean_nhwc_kernel(const float* __restrict__ in, float* __restrict__ out) {
    __shared__ float sm[256];
    int n = blockIdx.x;
    int c = threadIdx.x & 63, q = threadIdx.x >> 6;
    float s = 0.f;
    for (int p = q; p < 441; p += 4) s += in[((size_t)n * 441 + p) * 64 + c];
    sm[threadIdx.x] = s;
    __syncthreads();
    if (q == 0) out[n * 64 + c] = (sm[c] + sm[c + 64] + sm[c + 128] + sm[c + 192]) * (1.0f / 441.0f);
}

// single block: fc1 (64x64, relu) then fc2 (10x64)
__global__ void fc_kernel(const float* __restrict__ mean, const float* __restrict__ fw1,
                          const float* __restrict__ fb1, const float* __restrict__ fw2,
                          const float* __restrict__ fb2, float* __restrict__ out) {
    __shared__ float m[4096];
    __shared__ float h1[4096];
    int tid = threadIdx.x;
    for (int i = tid; i < 4096; i += 256) m[i] = mean[i];
    __syncthreads();
    for (int i = tid; i < 4096; i += 256) {
        int n = i >> 6, j = i & 63;
        float s = fb1[j];
        for (int k = 0; k < 64; ++k) s = fmaf(m[n * 64 + k], fw1[j * 64 + k], s);
        h1[i] = fmaxf(s, 0.f);
    }
    __syncthreads();
    for (int i = tid; i < 640; i += 256) {
        int n = i / 10, j2 = i % 10;
        float s = fb2[j2];
        for (int j = 0; j < 64; ++j) s = fmaf(h1[n * 64 + j], fw2[j2 * 64 + j], s);
        out[i] = s;
    }
}

extern "C" void kernel_launch(void* const* d_in, const int* in_sizes, int n_in,
                              void* d_out, int out_size, void* d_ws, size_t ws_size,
                              hipStream_t stream) {
    const float* x   = (const float*)d_in[0];
    const float* w0  = (const float*)d_in[1];
    const float* b0  = (const float*)d_in[2];
    const float* w1  = (const float*)d_in[3];
    const float* b1  = (const float*)d_in[4];
    const float* w2  = (const float*)d_in[5];
    const float* b2  = (const float*)d_in[6];
    const float* w3  = (const float*)d_in[7];
    const float* b3  = (const float*)d_in[8];
    const float* w4  = (const float*)d_in[9];
    const float* b4  = (const float*)d_in[10];
    const float* w5  = (const float*)d_in[11];
    const float* b5  = (const float*)d_in[12];
    const float* fw1 = (const float*)d_in[13];
    const float* fb1 = (const float*)d_in[14];
    const float* fw2 = (const float*)d_in[15];
    const float* fb2 = (const float*)d_in[16];

    char* ws = (char*)d_ws;
    if (ws_size < 128827392ull) return;

    float* F0   = (float*)(ws + 0);
    u16*   WF1  = (u16*)(ws + 8192);
    u16*   WF2  = (u16*)(ws + 161792);
    u16*   WF3  = (u16*)(ws + 468992);
    u16*   WF4  = (u16*)(ws + 1083392);
    u16*   WF5  = (u16*)(ws + 2004992);
    float* MEANB= (float*)(ws + 2619392);
    float* XP   = (float*)(ws + 2635776);
    float* C5   = (float*)(ws + 5144576);
    u16*   A    = (u16*)(ws + 12369920);    // P1 / P3 / P5
    u16*   B    = (u16*)(ws + 87867392);    // P2 / P4
    const long P1LO = 14155776;   // 64*96*96*24
    const long P2LO = 10240000;   // 64*50*50*64
    const long P4LO = 4478976;    // 64*27*27*96

    // --- weight transforms ---
    hipLaunchKernelGGL(lift_w0T_kernel, dim3(5), dim3(256), 0, stream, w0, F0);
    hipLaunchKernelGGL(wfrag_kernel, dim3(150), dim3(256), 0, stream, w1, WF1, 12, 6, 1, 3, 38400);
    hipLaunchKernelGGL(wfrag_kernel, dim3(300), dim3(256), 0, stream, w2, WF2, 12, 12, 2, 3, 76800);
    hipLaunchKernelGGL(wfrag_kernel, dim3(600), dim3(256), 0, stream, w3, WF3, 24, 12, 2, 6, 153600);
    hipLaunchKernelGGL(wfrag_kernel, dim3(900), dim3(256), 0, stream, w4, WF4, 24, 24, 3, 6, 230400);
    hipLaunchKernelGGL(wfrag_kernel, dim3(600), dim3(256), 0, stream, w5, WF5, 16, 24, 3, 4, 153600);

    // --- input pad (fp32) ---
    hipMemsetAsync(XP, 0, 2508800, stream);
    hipLaunchKernelGGL(pad_x_kernel, dim3(2304), dim3(256), 0, stream, x, XP);

    // --- P1 halo prep + conv0 (P1: [96][96][24]) ---
    hipLaunchKernelGGL(prep_halo_kernel, dim3(2304), dim3(256), 0, stream,
                       A, P1LO, 64*96*96, 96, 96, 24);
    hipLaunchKernelGGL(conv0_kernel, dim3((64*92*23 + 255)/256), dim3(256), 0, stream,
                       XP, F0, b0, A, P1LO);

    // --- P2 halo prep + conv1 (+pool): P1 -> P2 [50][50][64] --- PMODE 0
    hipLaunchKernelGGL(prep_halo_kernel, dim3(625), dim3(256), 0, stream,
                       B, P2LO, 64*50*50, 50, 50, 64);
    hipLaunchKernelGGL((conv_mfma_kernel<32, 24, 3, 3, 3, 2, 4, true, 0, 64, true, 0>),
                       dim3(1536), dim3(256), 0, stream,
                       A, P1LO, WF1, 38400, b1, B, P2LO, (float*)nullptr,
                       96, 96, 92, 92, 46, 46, 12, 2, 50, 50);

    // --- P3 halo prep + conv2: P2 -> P3 (A) [50][50][64] --- PMODE 1
    hipLaunchKernelGGL(prep_halo_kernel, dim3(625), dim3(256), 0, stream,
                       A, P2LO, 64*50*50, 50, 50, 64);
    hipLaunchKernelGGL((conv_mfma_kernel<64, 64, 3, 3, 3, 1, 4, false, 0, 64, true, 1>),
                       dim3(768), dim3(256), 0, stream,
                       B, P2LO, WF2, 76800, b2, A, P2LO, (float*)nullptr,
                       50, 50, 46, 46, 0, 0, 12, 1, 50, 50);

    // --- P4 halo prep + conv3 (+pool): P3 -> P4 (B) [27][27][96] --- PMODE 0
    hipLaunchKernelGGL(prep_halo_kernel, dim3(183), dim3(256), 0, stream,
                       B, P4LO, 64*27*27, 27, 27, 96);
    hipLaunchKernelGGL((conv_mfma_kernel<64, 64, 6, 3, 3, 2, 2, true, 0, 96, true, 0>),
                       dim3(768), dim3(256), 0, stream,
                       A, P2LO, WF3, 153600, b3, B, P4LO, (float*)nullptr,
                       50, 50, 46, 46, 23, 23, 12, 1, 27, 27);

    // --- P5 halo prep + conv4: P4 -> P5 (A) [27][27][96] --- PMODE 1
    hipLaunchKernelGGL(prep_halo_kernel, dim3(183), dim3(256), 0, stream,
                       A, P4LO, 64*27*27, 27, 27, 96);
    hipLaunchKernelGGL((conv_mfma_kernel<96, 96, 6, 3, 2, 2, 2, false, 0, 96, true, 1>),
                       dim3(384), dim3(256), 0, stream,
                       B, P4LO, WF4, 230400, b4, A, P4LO, (float*)nullptr,
                       27, 27, 23, 23, 0, 0, 6, 1, 27, 27);

    // --- conv5: P5 -> C5 fp32 NHWC compact [21][21][64] --- PMODE 1
    hipLaunchKernelGGL((conv_mfma_kernel<96, 96, 4, 2, 2, 2, 2, false, 1, 96, false, 1>),
                       dim3(384), dim3(256), 0, stream,
                       A, P4LO, WF5, 153600, b5, (u16*)A, 0, C5,
                       27, 27, 21, 21, 0, 0, 6, 1, 27, 27);

    // --- mean + fc ---
    hipLaunchKernelGGL(mean_nhwc_kernel, dim3(64), dim3(256), 0, stream, C5, MEANB);
    hipLaunchKernelGGL(fc_kernel, dim3(1), dim3(256), 0, stream,
                       MEANB, fw1, fb1, fw2, fb2, (float*)d_out);
}

// Round 16
// 557.804 us; speedup vs baseline: 1.3054x; 1.0252x over previous
//
#include <hip/hip_runtime.h>
#include <hip/hip_bf16.h>

// ---------------------------------------------------------------------------
// C4 equivariant CNN, round 16: r15 (=r13 best, 571.8us) + launch fusion.
//  All independent front-of-pipeline work (6 weight transforms, input pad,
//  P1/P2 halo preps) merged into ONE setup_kernel: removes ~8 serialized
//  small launches (~3-6us each). Conv pipeline byte-identical to r15.
// ---------------------------------------------------------------------------

typedef short s16x8 __attribute__((ext_vector_type(8)));
typedef __bf16 bf16x8 __attribute__((ext_vector_type(8)));
typedef float f32x4 __attribute__((ext_vector_type(4)));
typedef unsigned short u16;
typedef unsigned int u32;

__device__ __forceinline__ u16 f2bf(float f) {      // RNE fp32 -> bf16 bits
    unsigned u = __float_as_uint(f);
    return (u16)((u + 0x7FFFu + ((u >> 16) & 1u)) >> 16);
}
__device__ __forceinline__ float bf2f(u16 h) {
    return __uint_as_float(((unsigned)h) << 16);
}

__device__ __forceinline__ void rot_src(int r, int K, int y, int x, int& sy, int& sx) {
    switch (r & 3) {
        case 0: sy = y;         sx = x;         break;
        case 1: sy = x;         sx = K - 1 - y; break;
        case 2: sy = K - 1 - y; sx = K - 1 - x; break;
        default: sy = K - 1 - x; sx = y;        break;
    }
}

// one element of the group-transform + split + B-fragment pack
__device__ __forceinline__ void wfrag_elem(const float* __restrict__ w,
                                           u16* __restrict__ wf,
                                           int O, int I, int KC, int NT,
                                           int total, int idx) {
    int j = idx & 7;
    int lane = (idx >> 3) & 63;
    int rest = idx >> 9;
    int nc = rest % NT; rest /= NT;
    int kc = rest % KC; int kpos = rest / KC;
    int ky = kpos / 5, kx = kpos % 5;
    int kk = ((lane >> 4) << 3) + j;
    int ic = kc * 32 + kk;
    int oc = nc * 16 + (lane & 15);
    float val = 0.f;
    if (ic < I * 4) {
        int o = oc >> 2, r = oc & 3, i = ic >> 2, s = ic & 3;
        int g = (s - r + 4) & 3;
        int sy, sx; rot_src(r, 5, ky, kx, sy, sx);
        val = w[(((o * I + i) * 4 + g) * 25) + sy * 5 + sx];
    }
    u16 hb = f2bf(val);
    u16 lb = f2bf(val - bf2f(hb));
    wf[idx] = hb;
    wf[idx + total] = lb;
}

__device__ __forceinline__ void prep_halo_elem(u16* __restrict__ buf, long LO,
                                               int idx, int Hp, int Wp, int ICO) {
    int c = idx % Wp; int t = idx / Wp;
    int r = t % Hp; int n = t / Hp;
    bool halo = (r < 2) || (r >= Hp - 2) || (c < 2) || (c >= Wp - 2);
    if (!halo) return;
    size_t base = (((size_t)n * Hp + r) * Wp + c) * ICO;
    s16x8 z = {0, 0, 0, 0, 0, 0, 0, 0};
    for (int cc = 0; cc < (ICO >> 3); ++cc) {
        *(s16x8*)(buf + base + cc * 8) = z;
        *(s16x8*)(buf + LO + base + cc * 8) = z;
    }
}

// segment layout (element counts):
//  [0,1176)            lift w0 -> F0T [49][24]
//  [1176,39576)        wfrag w1 (12,6,1,3)   38400
//  [39576,116376)      wfrag w2 (12,12,2,3)  76800
//  [116376,269976)     wfrag w3 (24,12,2,6)  153600
//  [269976,500376)     wfrag w4 (24,24,3,6)  230400
//  [500376,653976)     wfrag w5 (16,24,3,4)  153600
//  [653976,1243800)    pad_x (XP border pre-zeroed by memset)    589824
//  [1243800,1833624)   prep halo P1 (96,96,24)                   589824
//  [1833624,1993624)   prep halo P2 (50,50,64)                   160000
__global__ void setup_kernel(
        const float* __restrict__ w0, const float* __restrict__ w1,
        const float* __restrict__ w2, const float* __restrict__ w3,
        const float* __restrict__ w4, const float* __restrict__ w5,
        float* __restrict__ F0, u16* __restrict__ WF1, u16* __restrict__ WF2,
        u16* __restrict__ WF3, u16* __restrict__ WF4, u16* __restrict__ WF5,
        const float* __restrict__ x, float* __restrict__ xp,
        u16* __restrict__ P1, long P1LO, u16* __restrict__ P2, long P2LO) {
    int gid = blockIdx.x * blockDim.x + threadIdx.x;
    if (gid < 1176) {
        const int K = 7, KK = 49, OC = 24;
        int oc = gid % OC; int kk = gid / OC;
        int y = kk / K, xx = kk % K;
        int r = oc & 3, o = oc >> 2;
        int sy, sx; rot_src(r, K, y, xx, sy, sx);
        F0[gid] = w0[o * KK + sy * K + sx];
    } else if (gid < 39576) {
        wfrag_elem(w1, WF1, 12, 6, 1, 3, 38400, gid - 1176);
    } else if (gid < 116376) {
        wfrag_elem(w2, WF2, 12, 12, 2, 3, 76800, gid - 39576);
    } else if (gid < 269976) {
        wfrag_elem(w3, WF3, 24, 12, 2, 6, 153600, gid - 116376);
    } else if (gid < 500376) {
        wfrag_elem(w4, WF4, 24, 24, 3, 6, 230400, gid - 269976);
    } else if (gid < 653976) {
        wfrag_elem(w5, WF5, 16, 24, 3, 4, 153600, gid - 500376);
    } else if (gid < 1243800) {
        int idx = gid - 653976;
        int c = idx % 96; int t = idx / 96;
        int r = t % 96; int n = t / 96;
        xp[((size_t)n * 98 + r + 1) * 100 + c + 1] = x[idx];
    } else if (gid < 1833624) {
        prep_halo_elem(P1, P1LO, gid - 1243800, 96, 96, 24);
    } else if (gid < 1993624) {
        prep_halo_elem(P2, P2LO, gid - 1833624, 50, 50, 64);
    }
}

// zero the 2-thick halo border only (both planes); used mid-pipeline (P3/4/5)
__global__ void prep_halo_kernel(u16* __restrict__ buf, long LO, int NHW,
                                 int Hp, int Wp, int ICO) {
    int idx = blockIdx.x * blockDim.x + threadIdx.x;
    if (idx >= NHW) return;
    prep_halo_elem(buf, LO, idx, Hp, Wp, ICO);
}

// conv0: fp32 direct (IC=1, K=7, pad=1). One thread: ALL 24 oc x 4 x.
// P1: [64][96][96][24] hi|lo, halo 2. Full 48B lines per pixel.
__global__ __launch_bounds__(256) void conv0_kernel(
        const float* __restrict__ xp, const float* __restrict__ f0t,
        const float* __restrict__ b0, u16* __restrict__ p1, long p1LO) {
    int idx = blockIdx.x * blockDim.x + threadIdx.x;
    if (idx >= 64 * 92 * 23) return;
    int xq = idx % 23; int t = idx / 23;
    int oy = t % 92; int n = t / 92;
    float acc[24][4];
#pragma unroll
    for (int a = 0; a < 24; ++a)
#pragma unroll
        for (int b = 0; b < 4; ++b) acc[a][b] = 0.f;

    const float* ip = xp + ((size_t)n * 98 + oy) * 100 + xq * 4;
#pragma unroll
    for (int ky = 0; ky < 7; ++ky) {
        const float* row = ip + (size_t)ky * 100;
        float xv[12];
#pragma unroll
        for (int v = 0; v < 3; ++v)
            *reinterpret_cast<float4*>(&xv[4 * v]) =
                *reinterpret_cast<const float4*>(row + 4 * v);
#pragma unroll
        for (int kx = 0; kx < 7; ++kx) {
            const float* wp = f0t + (ky * 7 + kx) * 24;
#pragma unroll
            for (int qd = 0; qd < 6; ++qd) {
                float4 wv = *reinterpret_cast<const float4*>(wp + qd * 4);
#pragma unroll
                for (int jx = 0; jx < 4; ++jx) {
                    acc[qd * 4 + 0][jx] = fmaf(wv.x, xv[kx + jx], acc[qd * 4 + 0][jx]);
                    acc[qd * 4 + 1][jx] = fmaf(wv.y, xv[kx + jx], acc[qd * 4 + 1][jx]);
                    acc[qd * 4 + 2][jx] = fmaf(wv.z, xv[kx + jx], acc[qd * 4 + 2][jx]);
                    acc[qd * 4 + 3][jx] = fmaf(wv.w, xv[kx + jx], acc[qd * 4 + 3][jx]);
                }
            }
        }
    }
    float bv[6];
#pragma unroll
    for (int qd = 0; qd < 6; ++qd) bv[qd] = b0[qd];

    size_t ob = (((size_t)n * 96 + oy + 2) * 96 + xq * 4 + 2) * 24;
#pragma unroll
    for (int jx = 0; jx < 4; ++jx) {
        s16x8 hv[3], lv[3];
#pragma unroll
        for (int cc = 0; cc < 3; ++cc)
#pragma unroll
            for (int e = 0; e < 8; ++e) {
                int ch = cc * 8 + e;
                float v = fmaxf(acc[ch][jx] + bv[ch >> 2], 0.f);
                u16 hb = f2bf(v);
                u16 lb = f2bf(v - bf2f(hb));
                hv[cc][e] = (short)hb; lv[cc][e] = (short)lb;
            }
#pragma unroll
        for (int cc = 0; cc < 3; ++cc) {
            *(s16x8*)(p1 + ob + jx * 24 + cc * 8) = hv[cc];
            *(s16x8*)(p1 + p1LO + ob + jx * 24 + cc * 8) = lv[cc];
        }
    }
}

// ---------------------------------------------------------------------------
// MFMA conv. wave = MT x-tiles x NTW oc-tiles x CR rows; block = SW row-groups
// x OG oc-groups. KC channel passes (32ch hi+lo staged per pass, swizzled).
// PMODE 1: full A+B ping-pong (fits when acc tile small).
// PMODE 0: B-only ping-pong, A loaded per-m inside window (big acc tiles).
// ---------------------------------------------------------------------------
template <int IC32, int ICIN, int NT, int NTW, int MT, int CR, int SW, bool POOL,
          int XOFF, int OCO, bool TRANS, int PMODE>
__global__ __launch_bounds__(SW*(NT/NTW)*64, 2) void conv_mfma_kernel(
        const u16* __restrict__ act, long actLO,
        const u16* __restrict__ wf, int wfLO,
        const float* __restrict__ bias,
        u16* __restrict__ outP, long outLO,
        float* __restrict__ outF,
        int Hp, int Wp, int OH, int OW, int PH, int POW,
        int NRG, int NXS, int HpO, int WpO) {
    constexpr int OG = NT / NTW;
    constexpr int NW = SW * OG;
    constexpr int KC = IC32 / 32;
    constexpr int WT = MT * 16 + 4 + XOFF;
    constexpr int R  = CR * SW + 4;
    constexpr int CHUNKS = R * WT * 8;          // 16B chunks per pass (hi+lo)
    constexpr int TROWS = POOL ? SW : CR * SW;  // output rows per block
    constexpr int TX = POOL ? MT * 8 : MT * 16; // output x per block
    constexpr int SX = OCO + 4;                 // u32 stride per x (+16B pad)
    constexpr int STAGE_B = CHUNKS * 16;
    constexpr int TRAN_B = TRANS ? TROWS * TX * SX * 4 : 0;
    constexpr int LDSB = STAGE_B > TRAN_B ? STAGE_B : TRAN_B;
    __shared__ __align__(16) char ldsraw[LDSB];
    u16* lds = (u16*)ldsraw;

    // bijective XCD swizzle (grid always a multiple of 8)
    int q8 = gridDim.x >> 3;
    int wid = (blockIdx.x & 7) * q8 + (blockIdx.x >> 3);
    int xs = wid % NXS; int t0 = wid / NXS;
    int rgrp = t0 % NRG; int n = t0 / NRG;

    int BR = rgrp * (CR * SW);      // conv-row base of block
    int rbase = BR + XOFF;          // input row base
    int xbase = xs * (MT * 16);     // conv-x base

    int tid = threadIdx.x;
    int wv = tid >> 6;
    int lane = tid & 63;
    int l15 = lane & 15, lg = lane >> 4;
    int og = wv % OG, rg = wv / OG;

    f32x4 accP[CR][MT][NTW], accQ[CR][MT][NTW];
#pragma unroll
    for (int cr = 0; cr < CR; ++cr)
#pragma unroll
        for (int m = 0; m < MT; ++m)
#pragma unroll
            for (int nc = 0; nc < NTW; ++nc) {
                accP[cr][m][nc] = f32x4{0.f, 0.f, 0.f, 0.f};
                accQ[cr][m][nc] = f32x4{0.f, 0.f, 0.f, 0.f};
            }

    const u16* wfl = wf + (size_t)lane * 8;
    const u16* actn = act + ((size_t)n * Hp) * Wp * ICIN;

    for (int kcp = 0; kcp < KC; ++kcp) {
        if (kcp) __syncthreads();
        // stage channels 32*kcp..+31, both planes, chunk-swizzled; chunks
        // beyond ICIN are zero-filled here (P1 stores only 24 real channels)
        for (int u = tid; u < CHUNKS; u += NW * 64) {
            int c = u & 7; int rest = u >> 3;
            int xl = rest % WT; int row = rest / WT;
            int cg = c ^ (xl & 7);
            int sp = cg >> 2, cc4 = cg & 3;
            int gx = xbase + xl, gr = rbase + row;
            int ch0 = (kcp * 4 + cc4) * 8;
            s16x8 v = {0, 0, 0, 0, 0, 0, 0, 0};
            if (gx < Wp && gr < Hp && ch0 < ICIN)
                v = *(const s16x8*)(actn + (size_t)sp * actLO +
                      ((size_t)gr * Wp + gx) * ICIN + ch0);
            *(s16x8*)&lds[(size_t)u * 8] = v;
        }
        __syncthreads();

        auto loadB = [&](int w, bf16x8 (&bh)[NTW], bf16x8 (&bl)[NTW]) {
            const u16* bp = wfl + ((size_t)(w * KC + kcp) * NT + og * NTW) * 512;
#pragma unroll
            for (int nc = 0; nc < NTW; ++nc) {
                bh[nc] = *(const bf16x8*)(bp + nc * 512);
                bl[nc] = *(const bf16x8*)(bp + nc * 512 + wfLO);
            }
        };

        if constexpr (PMODE == 1) {
            // ---- full A+B ping-pong (register budget permits) ----
            auto loadA = [&](int w, bf16x8 (&ah)[MT][CR], bf16x8 (&al)[MT][CR]) {
                int wky = w / 5, wkx = w - wky * 5;
#pragma unroll
                for (int m = 0; m < MT; ++m) {
                    int xl = m * 16 + XOFF + l15 + wkx;
                    int sw = xl & 7;
#pragma unroll
                    for (int cr = 0; cr < CR; ++cr) {
                        int row = rg * CR + cr + wky;
                        int base = (row * WT + xl) * 8;
                        ah[m][cr] = *(const bf16x8*)&lds[(size_t)(base + (lg ^ sw)) * 8];
                        al[m][cr] = *(const bf16x8*)&lds[(size_t)(base + ((4 + lg) ^ sw)) * 8];
                    }
                }
            };
            auto mfmaBlk = [&](bf16x8 (&bh)[NTW], bf16x8 (&bl)[NTW],
                               bf16x8 (&ah)[MT][CR], bf16x8 (&al)[MT][CR]) {
#pragma unroll
                for (int m = 0; m < MT; ++m)
#pragma unroll
                    for (int nc = 0; nc < NTW; ++nc)
#pragma unroll
                        for (int cr = 0; cr < CR; ++cr) {
                            accP[cr][m][nc] = __builtin_amdgcn_mfma_f32_16x16x32_bf16(
                                ah[m][cr], bh[nc], accP[cr][m][nc], 0, 0, 0);
                            accQ[cr][m][nc] = __builtin_amdgcn_mfma_f32_16x16x32_bf16(
                                ah[m][cr], bl[nc], accQ[cr][m][nc], 0, 0, 0);
                            accQ[cr][m][nc] = __builtin_amdgcn_mfma_f32_16x16x32_bf16(
                                al[m][cr], bh[nc], accQ[cr][m][nc], 0, 0, 0);
                        }
            };
            bf16x8 bhX[NTW], blX[NTW], ahX[MT][CR], alX[MT][CR];
            bf16x8 bhY[NTW], blY[NTW], ahY[MT][CR], alY[MT][CR];
            loadB(0, bhX, blX); loadA(0, ahX, alX);
            for (int t = 0; t < 12; ++t) {
                loadB(2 * t + 1, bhY, blY); loadA(2 * t + 1, ahY, alY);
                mfmaBlk(bhX, blX, ahX, alX);
                loadB(2 * t + 2, bhX, blX); loadA(2 * t + 2, ahX, alX);
                mfmaBlk(bhY, blY, ahY, alY);
            }
            mfmaBlk(bhX, blX, ahX, alX);
        } else {
            // ---- B-only ping-pong; A per-m inside window (no spill) ----
            auto window = [&](int w, bf16x8 (&bh)[NTW], bf16x8 (&bl)[NTW]) {
                int wky = w / 5, wkx = w - wky * 5;
#pragma unroll
                for (int m = 0; m < MT; ++m) {
                    int xl = m * 16 + XOFF + l15 + wkx;
                    int sw = xl & 7;
                    bf16x8 ah[CR], al[CR];
#pragma unroll
                    for (int cr = 0; cr < CR; ++cr) {
                        int row = rg * CR + cr + wky;
                        int base = (row * WT + xl) * 8;
                        ah[cr] = *(const bf16x8*)&lds[(size_t)(base + (lg ^ sw)) * 8];
                        al[cr] = *(const bf16x8*)&lds[(size_t)(base + ((4 + lg) ^ sw)) * 8];
                    }
#pragma unroll
                    for (int nc = 0; nc < NTW; ++nc)
#pragma unroll
                        for (int cr = 0; cr < CR; ++cr) {
                            accP[cr][m][nc] = __builtin_amdgcn_mfma_f32_16x16x32_bf16(
                                ah[cr], bh[nc], accP[cr][m][nc], 0, 0, 0);
                            accQ[cr][m][nc] = __builtin_amdgcn_mfma_f32_16x16x32_bf16(
                                ah[cr], bl[nc], accQ[cr][m][nc], 0, 0, 0);
                            accQ[cr][m][nc] = __builtin_amdgcn_mfma_f32_16x16x32_bf16(
                                al[cr], bh[nc], accQ[cr][m][nc], 0, 0, 0);
                        }
                }
            };
            bf16x8 bhX[NTW], blX[NTW], bhY[NTW], blY[NTW];
            loadB(0, bhX, blX);
            for (int t = 0; t < 12; ++t) {
                loadB(2 * t + 1, bhY, blY);
                window(2 * t, bhX, blX);
                loadB(2 * t + 2, bhX, blX);
                window(2 * t + 1, bhY, blY);
            }
            window(24, bhX, blX);
        }
    }

    if constexpr (TRANS) {
        // ---- transposed epilogue: acc -> LDS u32(hi|lo) -> full-line stores
        __syncthreads();
        u32* ldsw = (u32*)ldsraw;
#pragma unroll
        for (int nc = 0; nc < NTW; ++nc) {
            int oc = (og * NTW + nc) * 16 + l15;
            float bv = bias[oc >> 2];
#pragma unroll
            for (int m = 0; m < MT; ++m) {
                if constexpr (POOL) {
                    float c0[4], c1[4];
#pragma unroll
                    for (int j = 0; j < 4; ++j) {
                        c0[j] = accP[0][m][nc][j] + accQ[0][m][nc][j];
                        c1[j] = accP[1][m][nc][j] + accQ[1][m][nc][j];
                    }
#pragma unroll
                    for (int a2 = 0; a2 < 2; ++a2) {
                        float mx = fmaxf(fmaxf(c0[2 * a2], c0[2 * a2 + 1]),
                                         fmaxf(c1[2 * a2], c1[2 * a2 + 1]));
                        float v = fmaxf(mx + bv, 0.f);
                        u16 hb = f2bf(v);
                        u16 lb = f2bf(v - bf2f(hb));
                        int px = m * 8 + lg * 2 + a2;
                        ldsw[(rg * TX + px) * SX + oc] = ((u32)hb << 16) | lb;
                    }
                } else {
#pragma unroll
                    for (int cr = 0; cr < CR; ++cr)
#pragma unroll
                        for (int j = 0; j < 4; ++j) {
                            float v = fmaxf(accP[cr][m][nc][j] + accQ[cr][m][nc][j] + bv, 0.f);
                            u16 hb = f2bf(v);
                            u16 lb = f2bf(v - bf2f(hb));
                            int xloc = m * 16 + lg * 4 + j;
                            ldsw[((rg * CR + cr) * TX + xloc) * SX + oc] =
                                ((u32)hb << 16) | lb;
                        }
                }
            }
        }
        __syncthreads();
        constexpr int CPX = OCO / 8;               // chunks per pixel per plane
        constexpr int TOT = TROWS * TX * 2 * CPX;
        int OHL = POOL ? PH : OH;
        int OWL = POOL ? POW : OW;
        int obr = POOL ? rgrp * SW : BR;
        int obx = POOL ? (xbase >> 1) : xbase;
        for (int u = tid; u < TOT; u += NW * 64) {
            int c = u % CPX; int rest = u / CPX;
            int pl = rest & 1; rest >>= 1;
            int x = rest % TX; int row = rest / TX;
            int gr = obr + row, gx = obx + x;
            if (gr >= OHL || gx >= OWL) continue;
            s16x8 v = {0, 0, 0, 0, 0, 0, 0, 0};
            if (c * 8 < NT * 16) {
                const u32* p = &ldsw[(row * TX + x) * SX + c * 8];
                uint4 w0 = *(const uint4*)p;
                uint4 w1 = *(const uint4*)(p + 4);
                if (pl == 0) {
                    v[0] = (short)(w0.x >> 16); v[1] = (short)(w0.y >> 16);
                    v[2] = (short)(w0.z >> 16); v[3] = (short)(w0.w >> 16);
                    v[4] = (short)(w1.x >> 16); v[5] = (short)(w1.y >> 16);
                    v[6] = (short)(w1.z >> 16); v[7] = (short)(w1.w >> 16);
                } else {
                    v[0] = (short)(w0.x & 0xffff); v[1] = (short)(w0.y & 0xffff);
                    v[2] = (short)(w0.z & 0xffff); v[3] = (short)(w0.w & 0xffff);
                    v[4] = (short)(w1.x & 0xffff); v[5] = (short)(w1.y & 0xffff);
                    v[6] = (short)(w1.z & 0xffff); v[7] = (short)(w1.w & 0xffff);
                }
            }
            *(s16x8*)(outP + (size_t)pl * outLO +
                      (((size_t)n * HpO + gr + 2) * WpO + gx + 2) * OCO + c * 8) = v;
        }
    } else {
        // ---- direct fp32 epilogue (conv5 -> compact NHWC for mean) ----
#pragma unroll
        for (int nc = 0; nc < NTW; ++nc) {
            int oc = (og * NTW + nc) * 16 + l15;
            float bv = bias[oc >> 2];
#pragma unroll
            for (int m = 0; m < MT; ++m) {
                int gx0 = xbase + m * 16;
#pragma unroll
                for (int cr = 0; cr < CR; ++cr) {
                    int oy = BR + rg * CR + cr;
                    if (oy < OH) {
#pragma unroll
                        for (int j = 0; j < 4; ++j) {
                            int gx = gx0 + lg * 4 + j;
                            if (gx < OW) {
                                float v = fmaxf(accP[cr][m][nc][j] + accQ[cr][m][nc][j] + bv, 0.f);
                                outF[(((size_t)n * OH + oy) * OW + gx) * (NT * 16) + oc] = v;
                            }
                        }
                    }
                }
            }
        }
    }
}

// mean over 21x21 spatial of NHWC fp32 [64][21][21][64] -> (64,64)
__global__ void mean_nhwc_kernel(const float* __restrict__ in, float* __restrict__ out) {
    __shared__ float sm[256];
    int n = blockIdx.x;
    int c = threadIdx.x & 63, q = threadIdx.x >> 6;
    float s = 0.f;
    for (int p = q; p < 441; p += 4) s += in[((size_t)n * 441 + p) * 64 + c];
    sm[threadIdx.x] = s;
    __syncthreads();
    if (q == 0) out[n * 64 + c] = (sm[c] + sm[c + 64] + sm[c + 128] + sm[c + 192]) * (1.0f / 441.0f);
}

// single block: fc1 (64x64, relu) then fc2 (10x64)
__global__ void fc_kernel(const float* __restrict__ mean, const float* __restrict__ fw1,
                          const float* __restrict__ fb1, const float* __restrict__ fw2,
                          const float* __restrict__ fb2, float* __restrict__ out) {
    __shared__ float m[4096];
    __shared__ float h1[4096];
    int tid = threadIdx.x;
    for (int i = tid; i < 4096; i += 256) m[i] = mean[i];
    __syncthreads();
    for (int i = tid; i < 4096; i += 256) {
        int n = i >> 6, j = i & 63;
        float s = fb1[j];
        for (int k = 0; k < 64; ++k) s = fmaf(m[n * 64 + k], fw1[j * 64 + k], s);
        h1[i] = fmaxf(s, 0.f);
    }
    __syncthreads();
    for (int i = tid; i < 640; i += 256) {
        int n = i / 10, j2 = i % 10;
        float s = fb2[j2];
        for (int j = 0; j < 64; ++j) s = fmaf(h1[n * 64 + j], fw2[j2 * 64 + j], s);
        out[i] = s;
    }
}

extern "C" void kernel_launch(void* const* d_in, const int* in_sizes, int n_in,
                              void* d_out, int out_size, void* d_ws, size_t ws_size,
                              hipStream_t stream) {
    const float* x   = (const float*)d_in[0];
    const float* w0  = (const float*)d_in[1];
    const float* b0  = (const float*)d_in[2];
    const float* w1  = (const float*)d_in[3];
    const float* b1  = (const float*)d_in[4];
    const float* w2  = (const float*)d_in[5];
    const float* b2  = (const float*)d_in[6];
    const float* w3  = (const float*)d_in[7];
    const float* b3  = (const float*)d_in[8];
    const float* w4  = (const float*)d_in[9];
    const float* b4  = (const float*)d_in[10];
    const float* w5  = (const float*)d_in[11];
    const float* b5  = (const float*)d_in[12];
    const float* fw1 = (const float*)d_in[13];
    const float* fb1 = (const float*)d_in[14];
    const float* fw2 = (const float*)d_in[15];
    const float* fb2 = (const float*)d_in[16];

    char* ws = (char*)d_ws;
    if (ws_size < 128827392ull) return;

    float* F0   = (float*)(ws + 0);
    u16*   WF1  = (u16*)(ws + 8192);
    u16*   WF2  = (u16*)(ws + 161792);
    u16*   WF3  = (u16*)(ws + 468992);
    u16*   WF4  = (u16*)(ws + 1083392);
    u16*   WF5  = (u16*)(ws + 2004992);
    float* MEANB= (float*)(ws + 2619392);
    float* XP   = (float*)(ws + 2635776);
    float* C5   = (float*)(ws + 5144576);
    u16*   A    = (u16*)(ws + 12369920);    // P1 / P3 / P5
    u16*   B    = (u16*)(ws + 87867392);    // P2 / P4
    const long P1LO = 14155776;   // 64*96*96*24
    const long P2LO = 10240000;   // 64*50*50*64
    const long P4LO = 4478976;    // 64*27*27*96

    // --- fused setup: XP border zero + transforms + pad_x + P1/P2 halo prep
    hipMemsetAsync(XP, 0, 2508800, stream);
    hipLaunchKernelGGL(setup_kernel, dim3((1993624 + 255) / 256), dim3(256), 0, stream,
                       w0, w1, w2, w3, w4, w5,
                       F0, WF1, WF2, WF3, WF4, WF5,
                       x, XP, A, P1LO, B, P2LO);

    // --- conv0 -> P1 (A) ---
    hipLaunchKernelGGL(conv0_kernel, dim3((64*92*23 + 255)/256), dim3(256), 0, stream,
                       XP, F0, b0, A, P1LO);

    // --- conv1 (+pool): P1 -> P2 [50][50][64] --- PMODE 0
    hipLaunchKernelGGL((conv_mfma_kernel<32, 24, 3, 3, 3, 2, 4, true, 0, 64, true, 0>),
                       dim3(1536), dim3(256), 0, stream,
                       A, P1LO, WF1, 38400, b1, B, P2LO, (float*)nullptr,
                       96, 96, 92, 92, 46, 46, 12, 2, 50, 50);

    // --- P3 halo prep + conv2: P2 -> P3 (A) [50][50][64] --- PMODE 1
    hipLaunchKernelGGL(prep_halo_kernel, dim3(625), dim3(256), 0, stream,
                       A, P2LO, 64*50*50, 50, 50, 64);
    hipLaunchKernelGGL((conv_mfma_kernel<64, 64, 3, 3, 3, 1, 4, false, 0, 64, true, 1>),
                       dim3(768), dim3(256), 0, stream,
                       B, P2LO, WF2, 76800, b2, A, P2LO, (float*)nullptr,
                       50, 50, 46, 46, 0, 0, 12, 1, 50, 50);

    // --- P4 halo prep + conv3 (+pool): P3 -> P4 (B) [27][27][96] --- PMODE 0
    hipLaunchKernelGGL(prep_halo_kernel, dim3(183), dim3(256), 0, stream,
                       B, P4LO, 64*27*27, 27, 27, 96);
    hipLaunchKernelGGL((conv_mfma_kernel<64, 64, 6, 3, 3, 2, 2, true, 0, 96, true, 0>),
                       dim3(768), dim3(256), 0, stream,
                       A, P2LO, WF3, 153600, b3, B, P4LO, (float*)nullptr,
                       50, 50, 46, 46, 23, 23, 12, 1, 27, 27);

    // --- P5 halo prep + conv4: P4 -> P5 (A) [27][27][96] --- PMODE 1
    hipLaunchKernelGGL(prep_halo_kernel, dim3(183), dim3(256), 0, stream,
                       A, P4LO, 64*27*27, 27, 27, 96);
    hipLaunchKernelGGL((conv_mfma_kernel<96, 96, 6, 3, 2, 2, 2, false, 0, 96, true, 1>),
                       dim3(384), dim3(256), 0, stream,
                       B, P4LO, WF4, 230400, b4, A, P4LO, (float*)nullptr,
                       27, 27, 23, 23, 0, 0, 6, 1, 27, 27);

    // --- conv5: P5 -> C5 fp32 NHWC compact [21][21][64] --- PMODE 1
    hipLaunchKernelGGL((conv_mfma_kernel<96, 96, 4, 2, 2, 2, 2, false, 1, 96, false, 1>),
                       dim3(384), dim3(256), 0, stream,
                       A, P4LO, WF5, 153600, b5, (u16*)A, 0, C5,
                       27, 27, 21, 21, 0, 0, 6, 1, 27, 27);

    // --- mean + fc ---
    hipLaunchKernelGGL(mean_nhwc_kernel, dim3(64), dim3(256), 0, stream, C5, MEANB);
    hipLaunchKernelGGL(fc_kernel, dim3(1), dim3(256), 0, stream,
                       MEANB, fw1, fb1, fw2, fb2, (float*)d_out);
}

// Round 17
// 545.757 us; speedup vs baseline: 1.3342x; 1.0221x over previous
//
#include <hip/hip_runtime.h>
#include <hip/hip_bf16.h>

// ---------------------------------------------------------------------------
// C4 equivariant CNN, round 17: r16 + mid-pipeline halo preps folded into the
// producing convs (conv2 zeroes P3 halo, conv3 -> P4, conv4 -> P5): regions
// are disjoint from each conv's reads/writes, so the standalone prep launches
// are removed. Conv pipeline otherwise byte-identical to r16 (557.8us).
// ---------------------------------------------------------------------------

typedef short s16x8 __attribute__((ext_vector_type(8)));
typedef __bf16 bf16x8 __attribute__((ext_vector_type(8)));
typedef float f32x4 __attribute__((ext_vector_type(4)));
typedef unsigned short u16;
typedef unsigned int u32;

__device__ __forceinline__ u16 f2bf(float f) {      // RNE fp32 -> bf16 bits
    unsigned u = __float_as_uint(f);
    return (u16)((u + 0x7FFFu + ((u >> 16) & 1u)) >> 16);
}
__device__ __forceinline__ float bf2f(u16 h) {
    return __uint_as_float(((unsigned)h) << 16);
}

__device__ __forceinline__ void rot_src(int r, int K, int y, int x, int& sy, int& sx) {
    switch (r & 3) {
        case 0: sy = y;         sx = x;         break;
        case 1: sy = x;         sx = K - 1 - y; break;
        case 2: sy = K - 1 - y; sx = K - 1 - x; break;
        default: sy = K - 1 - x; sx = y;        break;
    }
}

// one element of the group-transform + split + B-fragment pack
__device__ __forceinline__ void wfrag_elem(const float* __restrict__ w,
                                           u16* __restrict__ wf,
                                           int O, int I, int KC, int NT,
                                           int total, int idx) {
    int j = idx & 7;
    int lane = (idx >> 3) & 63;
    int rest = idx >> 9;
    int nc = rest % NT; rest /= NT;
    int kc = rest % KC; int kpos = rest / KC;
    int ky = kpos / 5, kx = kpos % 5;
    int kk = ((lane >> 4) << 3) + j;
    int ic = kc * 32 + kk;
    int oc = nc * 16 + (lane & 15);
    float val = 0.f;
    if (ic < I * 4) {
        int o = oc >> 2, r = oc & 3, i = ic >> 2, s = ic & 3;
        int g = (s - r + 4) & 3;
        int sy, sx; rot_src(r, 5, ky, kx, sy, sx);
        val = w[(((o * I + i) * 4 + g) * 25) + sy * 5 + sx];
    }
    u16 hb = f2bf(val);
    u16 lb = f2bf(val - bf2f(hb));
    wf[idx] = hb;
    wf[idx + total] = lb;
}

__device__ __forceinline__ void prep_halo_elem(u16* __restrict__ buf, long LO,
                                               int idx, int Hp, int Wp, int ICO) {
    int c = idx % Wp; int t = idx / Wp;
    int r = t % Hp; int n = t / Hp;
    bool halo = (r < 2) || (r >= Hp - 2) || (c < 2) || (c >= Wp - 2);
    if (!halo) return;
    size_t base = (((size_t)n * Hp + r) * Wp + c) * ICO;
    s16x8 z = {0, 0, 0, 0, 0, 0, 0, 0};
    for (int cc = 0; cc < (ICO >> 3); ++cc) {
        *(s16x8*)(buf + base + cc * 8) = z;
        *(s16x8*)(buf + LO + base + cc * 8) = z;
    }
}

// segment layout (element counts):
//  [0,1176)            lift w0 -> F0T [49][24]
//  [1176,39576)        wfrag w1 (12,6,1,3)   38400
//  [39576,116376)      wfrag w2 (12,12,2,3)  76800
//  [116376,269976)     wfrag w3 (24,12,2,6)  153600
//  [269976,500376)     wfrag w4 (24,24,3,6)  230400
//  [500376,653976)     wfrag w5 (16,24,3,4)  153600
//  [653976,1243800)    pad_x (XP border pre-zeroed by memset)    589824
//  [1243800,1833624)   prep halo P1 (96,96,24)                   589824
//  [1833624,1993624)   prep halo P2 (50,50,64)                   160000
__global__ void setup_kernel(
        const float* __restrict__ w0, const float* __restrict__ w1,
        const float* __restrict__ w2, const float* __restrict__ w3,
        const float* __restrict__ w4, const float* __restrict__ w5,
        float* __restrict__ F0, u16* __restrict__ WF1, u16* __restrict__ WF2,
        u16* __restrict__ WF3, u16* __restrict__ WF4, u16* __restrict__ WF5,
        const float* __restrict__ x, float* __restrict__ xp,
        u16* __restrict__ P1, long P1LO, u16* __restrict__ P2, long P2LO) {
    int gid = blockIdx.x * blockDim.x + threadIdx.x;
    if (gid < 1176) {
        const int K = 7, KK = 49, OC = 24;
        int oc = gid % OC; int kk = gid / OC;
        int y = kk / K, xx = kk % K;
        int r = oc & 3, o = oc >> 2;
        int sy, sx; rot_src(r, K, y, xx, sy, sx);
        F0[gid] = w0[o * KK + sy * K + sx];
    } else if (gid < 39576) {
        wfrag_elem(w1, WF1, 12, 6, 1, 3, 38400, gid - 1176);
    } else if (gid < 116376) {
        wfrag_elem(w2, WF2, 12, 12, 2, 3, 76800, gid - 39576);
    } else if (gid < 269976) {
        wfrag_elem(w3, WF3, 24, 12, 2, 6, 153600, gid - 116376);
    } else if (gid < 500376) {
        wfrag_elem(w4, WF4, 24, 24, 3, 6, 230400, gid - 269976);
    } else if (gid < 653976) {
        wfrag_elem(w5, WF5, 16, 24, 3, 4, 153600, gid - 500376);
    } else if (gid < 1243800) {
        int idx = gid - 653976;
        int c = idx % 96; int t = idx / 96;
        int r = t % 96; int n = t / 96;
        xp[((size_t)n * 98 + r + 1) * 100 + c + 1] = x[idx];
    } else if (gid < 1833624) {
        prep_halo_elem(P1, P1LO, gid - 1243800, 96, 96, 24);
    } else if (gid < 1993624) {
        prep_halo_elem(P2, P2LO, gid - 1833624, 50, 50, 64);
    }
}

// conv0: fp32 direct (IC=1, K=7, pad=1). One thread: ALL 24 oc x 4 x.
// P1: [64][96][96][24] hi|lo, halo 2. Full 48B lines per pixel.
__global__ __launch_bounds__(256) void conv0_kernel(
        const float* __restrict__ xp, const float* __restrict__ f0t,
        const float* __restrict__ b0, u16* __restrict__ p1, long p1LO) {
    int idx = blockIdx.x * blockDim.x + threadIdx.x;
    if (idx >= 64 * 92 * 23) return;
    int xq = idx % 23; int t = idx / 23;
    int oy = t % 92; int n = t / 92;
    float acc[24][4];
#pragma unroll
    for (int a = 0; a < 24; ++a)
#pragma unroll
        for (int b = 0; b < 4; ++b) acc[a][b] = 0.f;

    const float* ip = xp + ((size_t)n * 98 + oy) * 100 + xq * 4;
#pragma unroll
    for (int ky = 0; ky < 7; ++ky) {
        const float* row = ip + (size_t)ky * 100;
        float xv[12];
#pragma unroll
        for (int v = 0; v < 3; ++v)
            *reinterpret_cast<float4*>(&xv[4 * v]) =
                *reinterpret_cast<const float4*>(row + 4 * v);
#pragma unroll
        for (int kx = 0; kx < 7; ++kx) {
            const float* wp = f0t + (ky * 7 + kx) * 24;
#pragma unroll
            for (int qd = 0; qd < 6; ++qd) {
                float4 wv = *reinterpret_cast<const float4*>(wp + qd * 4);
#pragma unroll
                for (int jx = 0; jx < 4; ++jx) {
                    acc[qd * 4 + 0][jx] = fmaf(wv.x, xv[kx + jx], acc[qd * 4 + 0][jx]);
                    acc[qd * 4 + 1][jx] = fmaf(wv.y, xv[kx + jx], acc[qd * 4 + 1][jx]);
                    acc[qd * 4 + 2][jx] = fmaf(wv.z, xv[kx + jx], acc[qd * 4 + 2][jx]);
                    acc[qd * 4 + 3][jx] = fmaf(wv.w, xv[kx + jx], acc[qd * 4 + 3][jx]);
                }
            }
        }
    }
    float bv[6];
#pragma unroll
    for (int qd = 0; qd < 6; ++qd) bv[qd] = b0[qd];

    size_t ob = (((size_t)n * 96 + oy + 2) * 96 + xq * 4 + 2) * 24;
#pragma unroll
    for (int jx = 0; jx < 4; ++jx) {
        s16x8 hv[3], lv[3];
#pragma unroll
        for (int cc = 0; cc < 3; ++cc)
#pragma unroll
            for (int e = 0; e < 8; ++e) {
                int ch = cc * 8 + e;
                float v = fmaxf(acc[ch][jx] + bv[ch >> 2], 0.f);
                u16 hb = f2bf(v);
                u16 lb = f2bf(v - bf2f(hb));
                hv[cc][e] = (short)hb; lv[cc][e] = (short)lb;
            }
#pragma unroll
        for (int cc = 0; cc < 3; ++cc) {
            *(s16x8*)(p1 + ob + jx * 24 + cc * 8) = hv[cc];
            *(s16x8*)(p1 + p1LO + ob + jx * 24 + cc * 8) = lv[cc];
        }
    }
}

// ---------------------------------------------------------------------------
// MFMA conv. wave = MT x-tiles x NTW oc-tiles x CR rows; block = SW row-groups
// x OG oc-groups. KC channel passes (32ch hi+lo staged per pass, swizzled).
// PMODE 1: full A+B ping-pong (fits when acc tile small).
// PMODE 0: B-only ping-pong, A loaded per-m inside window (big acc tiles).
// HPREP: this conv also zeroes its own output buffer's halo (disjoint from
// all its reads and interior writes; consumer runs in a later dispatch).
// ---------------------------------------------------------------------------
template <int IC32, int ICIN, int NT, int NTW, int MT, int CR, int SW, bool POOL,
          int XOFF, int OCO, bool TRANS, int PMODE, bool HPREP>
__global__ __launch_bounds__(SW*(NT/NTW)*64, 2) void conv_mfma_kernel(
        const u16* __restrict__ act, long actLO,
        const u16* __restrict__ wf, int wfLO,
        const float* __restrict__ bias,
        u16* __restrict__ outP, long outLO,
        float* __restrict__ outF,
        int Hp, int Wp, int OH, int OW, int PH, int POW,
        int NRG, int NXS, int HpO, int WpO, int NHWO) {
    constexpr int OG = NT / NTW;
    constexpr int NW = SW * OG;
    constexpr int KC = IC32 / 32;
    constexpr int WT = MT * 16 + 4 + XOFF;
    constexpr int R  = CR * SW + 4;
    constexpr int CHUNKS = R * WT * 8;          // 16B chunks per pass (hi+lo)
    constexpr int TROWS = POOL ? SW : CR * SW;  // output rows per block
    constexpr int TX = POOL ? MT * 8 : MT * 16; // output x per block
    constexpr int SX = OCO + 4;                 // u32 stride per x (+16B pad)
    constexpr int STAGE_B = CHUNKS * 16;
    constexpr int TRAN_B = TRANS ? TROWS * TX * SX * 4 : 0;
    constexpr int LDSB = STAGE_B > TRAN_B ? STAGE_B : TRAN_B;
    __shared__ __align__(16) char ldsraw[LDSB];
    u16* lds = (u16*)ldsraw;

    if constexpr (HPREP) {
        // fold the successor's halo prep into this conv (regions disjoint)
        int stride = gridDim.x * (NW * 64);
        for (int hidx = blockIdx.x * (NW * 64) + threadIdx.x; hidx < NHWO;
             hidx += stride)
            prep_halo_elem(outP, outLO, hidx, HpO, WpO, OCO);
    }

    // bijective XCD swizzle (grid always a multiple of 8)
    int q8 = gridDim.x >> 3;
    int wid = (blockIdx.x & 7) * q8 + (blockIdx.x >> 3);
    int xs = wid % NXS; int t0 = wid / NXS;
    int rgrp = t0 % NRG; int n = t0 / NRG;

    int BR = rgrp * (CR * SW);      // conv-row base of block
    int rbase = BR + XOFF;          // input row base
    int xbase = xs * (MT * 16);     // conv-x base

    int tid = threadIdx.x;
    int wv = tid >> 6;
    int lane = tid & 63;
    int l15 = lane & 15, lg = lane >> 4;
    int og = wv % OG, rg = wv / OG;

    f32x4 accP[CR][MT][NTW], accQ[CR][MT][NTW];
#pragma unroll
    for (int cr = 0; cr < CR; ++cr)
#pragma unroll
        for (int m = 0; m < MT; ++m)
#pragma unroll
            for (int nc = 0; nc < NTW; ++nc) {
                accP[cr][m][nc] = f32x4{0.f, 0.f, 0.f, 0.f};
                accQ[cr][m][nc] = f32x4{0.f, 0.f, 0.f, 0.f};
            }

    const u16* wfl = wf + (size_t)lane * 8;
    const u16* actn = act + ((size_t)n * Hp) * Wp * ICIN;

    for (int kcp = 0; kcp < KC; ++kcp) {
        if (kcp) __syncthreads();
        // stage channels 32*kcp..+31, both planes, chunk-swizzled; chunks
        // beyond ICIN are zero-filled here (P1 stores only 24 real channels)
        for (int u = tid; u < CHUNKS; u += NW * 64) {
            int c = u & 7; int rest = u >> 3;
            int xl = rest % WT; int row = rest / WT;
            int cg = c ^ (xl & 7);
            int sp = cg >> 2, cc4 = cg & 3;
            int gx = xbase + xl, gr = rbase + row;
            int ch0 = (kcp * 4 + cc4) * 8;
            s16x8 v = {0, 0, 0, 0, 0, 0, 0, 0};
            if (gx < Wp && gr < Hp && ch0 < ICIN)
                v = *(const s16x8*)(actn + (size_t)sp * actLO +
                      ((size_t)gr * Wp + gx) * ICIN + ch0);
            *(s16x8*)&lds[(size_t)u * 8] = v;
        }
        __syncthreads();

        auto loadB = [&](int w, bf16x8 (&bh)[NTW], bf16x8 (&bl)[NTW]) {
            const u16* bp = wfl + ((size_t)(w * KC + kcp) * NT + og * NTW) * 512;
#pragma unroll
            for (int nc = 0; nc < NTW; ++nc) {
                bh[nc] = *(const bf16x8*)(bp + nc * 512);
                bl[nc] = *(const bf16x8*)(bp + nc * 512 + wfLO);
            }
        };

        if constexpr (PMODE == 1) {
            // ---- full A+B ping-pong (register budget permits) ----
            auto loadA = [&](int w, bf16x8 (&ah)[MT][CR], bf16x8 (&al)[MT][CR]) {
                int wky = w / 5, wkx = w - wky * 5;
#pragma unroll
                for (int m = 0; m < MT; ++m) {
                    int xl = m * 16 + XOFF + l15 + wkx;
                    int sw = xl & 7;
#pragma unroll
                    for (int cr = 0; cr < CR; ++cr) {
                        int row = rg * CR + cr + wky;
                        int base = (row * WT + xl) * 8;
                        ah[m][cr] = *(const bf16x8*)&lds[(size_t)(base + (lg ^ sw)) * 8];
                        al[m][cr] = *(const bf16x8*)&lds[(size_t)(base + ((4 + lg) ^ sw)) * 8];
                    }
                }
            };
            auto mfmaBlk = [&](bf16x8 (&bh)[NTW], bf16x8 (&bl)[NTW],
                               bf16x8 (&ah)[MT][CR], bf16x8 (&al)[MT][CR]) {
#pragma unroll
                for (int m = 0; m < MT; ++m)
#pragma unroll
                    for (int nc = 0; nc < NTW; ++nc)
#pragma unroll
                        for (int cr = 0; cr < CR; ++cr) {
                            accP[cr][m][nc] = __builtin_amdgcn_mfma_f32_16x16x32_bf16(
                                ah[m][cr], bh[nc], accP[cr][m][nc], 0, 0, 0);
                            accQ[cr][m][nc] = __builtin_amdgcn_mfma_f32_16x16x32_bf16(
                                ah[m][cr], bl[nc], accQ[cr][m][nc], 0, 0, 0);
                            accQ[cr][m][nc] = __builtin_amdgcn_mfma_f32_16x16x32_bf16(
                                al[m][cr], bh[nc], accQ[cr][m][nc], 0, 0, 0);
                        }
            };
            bf16x8 bhX[NTW], blX[NTW], ahX[MT][CR], alX[MT][CR];
            bf16x8 bhY[NTW], blY[NTW], ahY[MT][CR], alY[MT][CR];
            loadB(0, bhX, blX); loadA(0, ahX, alX);
            for (int t = 0; t < 12; ++t) {
                loadB(2 * t + 1, bhY, blY); loadA(2 * t + 1, ahY, alY);
                mfmaBlk(bhX, blX, ahX, alX);
                loadB(2 * t + 2, bhX, blX); loadA(2 * t + 2, ahX, alX);
                mfmaBlk(bhY, blY, ahY, alY);
            }
            mfmaBlk(bhX, blX, ahX, alX);
        } else {
            // ---- B-only ping-pong; A per-m inside window (no spill) ----
            auto window = [&](int w, bf16x8 (&bh)[NTW], bf16x8 (&bl)[NTW]) {
                int wky = w / 5, wkx = w - wky * 5;
#pragma unroll
                for (int m = 0; m < MT; ++m) {
                    int xl = m * 16 + XOFF + l15 + wkx;
                    int sw = xl & 7;
                    bf16x8 ah[CR], al[CR];
#pragma unroll
                    for (int cr = 0; cr < CR; ++cr) {
                        int row = rg * CR + cr + wky;
                        int base = (row * WT + xl) * 8;
                        ah[cr] = *(const bf16x8*)&lds[(size_t)(base + (lg ^ sw)) * 8];
                        al[cr] = *(const bf16x8*)&lds[(size_t)(base + ((4 + lg) ^ sw)) * 8];
                    }
#pragma unroll
                    for (int nc = 0; nc < NTW; ++nc)
#pragma unroll
                        for (int cr = 0; cr < CR; ++cr) {
                            accP[cr][m][nc] = __builtin_amdgcn_mfma_f32_16x16x32_bf16(
                                ah[cr], bh[nc], accP[cr][m][nc], 0, 0, 0);
                            accQ[cr][m][nc] = __builtin_amdgcn_mfma_f32_16x16x32_bf16(
                                ah[cr], bl[nc], accQ[cr][m][nc], 0, 0, 0);
                            accQ[cr][m][nc] = __builtin_amdgcn_mfma_f32_16x16x32_bf16(
                                al[cr], bh[nc], accQ[cr][m][nc], 0, 0, 0);
                        }
                }
            };
            bf16x8 bhX[NTW], blX[NTW], bhY[NTW], blY[NTW];
            loadB(0, bhX, blX);
            for (int t = 0; t < 12; ++t) {
                loadB(2 * t + 1, bhY, blY);
                window(2 * t, bhX, blX);
                loadB(2 * t + 2, bhX, blX);
                window(2 * t + 1, bhY, blY);
            }
            window(24, bhX, blX);
        }
    }

    if constexpr (TRANS) {
        // ---- transposed epilogue: acc -> LDS u32(hi|lo) -> full-line stores
        __syncthreads();
        u32* ldsw = (u32*)ldsraw;
#pragma unroll
        for (int nc = 0; nc < NTW; ++nc) {
            int oc = (og * NTW + nc) * 16 + l15;
            float bv = bias[oc >> 2];
#pragma unroll
            for (int m = 0; m < MT; ++m) {
                if constexpr (POOL) {
                    float c0[4], c1[4];
#pragma unroll
                    for (int j = 0; j < 4; ++j) {
                        c0[j] = accP[0][m][nc][j] + accQ[0][m][nc][j];
                        c1[j] = accP[1][m][nc][j] + accQ[1][m][nc][j];
                    }
#pragma unroll
                    for (int a2 = 0; a2 < 2; ++a2) {
                        float mx = fmaxf(fmaxf(c0[2 * a2], c0[2 * a2 + 1]),
                                         fmaxf(c1[2 * a2], c1[2 * a2 + 1]));
                        float v = fmaxf(mx + bv, 0.f);
                        u16 hb = f2bf(v);
                        u16 lb = f2bf(v - bf2f(hb));
                        int px = m * 8 + lg * 2 + a2;
                        ldsw[(rg * TX + px) * SX + oc] = ((u32)hb << 16) | lb;
                    }
                } else {
#pragma unroll
                    for (int cr = 0; cr < CR; ++cr)
#pragma unroll
                        for (int j = 0; j < 4; ++j) {
                            float v = fmaxf(accP[cr][m][nc][j] + accQ[cr][m][nc][j] + bv, 0.f);
                            u16 hb = f2bf(v);
                            u16 lb = f2bf(v - bf2f(hb));
                            int xloc = m * 16 + lg * 4 + j;
                            ldsw[((rg * CR + cr) * TX + xloc) * SX + oc] =
                                ((u32)hb << 16) | lb;
                        }
                }
            }
        }
        __syncthreads();
        constexpr int CPX = OCO / 8;               // chunks per pixel per plane
        constexpr int TOT = TROWS * TX * 2 * CPX;
        int OHL = POOL ? PH : OH;
        int OWL = POOL ? POW : OW;
        int obr = POOL ? rgrp * SW : BR;
        int obx = POOL ? (xbase >> 1) : xbase;
        for (int u = tid; u < TOT; u += NW * 64) {
            int c = u % CPX; int rest = u / CPX;
            int pl = rest & 1; rest >>= 1;
            int x = rest % TX; int row = rest / TX;
            int gr = obr + row, gx = obx + x;
            if (gr >= OHL || gx >= OWL) continue;
            s16x8 v = {0, 0, 0, 0, 0, 0, 0, 0};
            if (c * 8 < NT * 16) {
                const u32* p = &ldsw[(row * TX + x) * SX + c * 8];
                uint4 w0 = *(const uint4*)p;
                uint4 w1 = *(const uint4*)(p + 4);
                if (pl == 0) {
                    v[0] = (short)(w0.x >> 16); v[1] = (short)(w0.y >> 16);
                    v[2] = (short)(w0.z >> 16); v[3] = (short)(w0.w >> 16);
                    v[4] = (short)(w1.x >> 16); v[5] = (short)(w1.y >> 16);
                    v[6] = (short)(w1.z >> 16); v[7] = (short)(w1.w >> 16);
                } else {
                    v[0] = (short)(w0.x & 0xffff); v[1] = (short)(w0.y & 0xffff);
                    v[2] = (short)(w0.z & 0xffff); v[3] = (short)(w0.w & 0xffff);
                    v[4] = (short)(w1.x & 0xffff); v[5] = (short)(w1.y & 0xffff);
                    v[6] = (short)(w1.z & 0xffff); v[7] = (short)(w1.w & 0xffff);
                }
            }
            *(s16x8*)(outP + (size_t)pl * outLO +
                      (((size_t)n * HpO + gr + 2) * WpO + gx + 2) * OCO + c * 8) = v;
        }
    } else {
        // ---- direct fp32 epilogue (conv5 -> compact NHWC for mean) ----
#pragma unroll
        for (int nc = 0; nc < NTW; ++nc) {
            int oc = (og * NTW + nc) * 16 + l15;
            float bv = bias[oc >> 2];
#pragma unroll
            for (int m = 0; m < MT; ++m) {
                int gx0 = xbase + m * 16;
#pragma unroll
                for (int cr = 0; cr < CR; ++cr) {
                    int oy = BR + rg * CR + cr;
                    if (oy < OH) {
#pragma unroll
                        for (int j = 0; j < 4; ++j) {
                            int gx = gx0 + lg * 4 + j;
                            if (gx < OW) {
                                float v = fmaxf(accP[cr][m][nc][j] + accQ[cr][m][nc][j] + bv, 0.f);
                                outF[(((size_t)n * OH + oy) * OW + gx) * (NT * 16) + oc] = v;
                            }
                        }
                    }
                }
            }
        }
    }
}

// mean over 21x21 spatial of NHWC fp32 [64][21][21][64] -> (64,64)
__global__ void mean_nhwc_kernel(const float* __restrict__ in, float* __restrict__ out) {
    __shared__ float sm[256];
    int n = blockIdx.x;
    int c = threadIdx.x & 63, q = threadIdx.x >> 6;
    float s = 0.f;
    for (int p = q; p < 441; p += 4) s += in[((size_t)n * 441 + p) * 64 + c];
    sm[threadIdx.x] = s;
    __syncthreads();
    if (q == 0) out[n * 64 + c] = (sm[c] + sm[c + 64] + sm[c + 128] + sm[c + 192]) * (1.0f / 441.0f);
}

// single block: fc1 (64x64, relu) then fc2 (10x64)
__global__ void fc_kernel(const float* __restrict__ mean, const float* __restrict__ fw1,
                          const float* __restrict__ fb1, const float* __restrict__ fw2,
                          const float* __restrict__ fb2, float* __restrict__ out) {
    __shared__ float m[4096];
    __shared__ float h1[4096];
    int tid = threadIdx.x;
    for (int i = tid; i < 4096; i += 256) m[i] = mean[i];
    __syncthreads();
    for (int i = tid; i < 4096; i += 256) {
        int n = i >> 6, j = i & 63;
        float s = fb1[j];
        for (int k = 0; k < 64; ++k) s = fmaf(m[n * 64 + k], fw1[j * 64 + k], s);
        h1[i] = fmaxf(s, 0.f);
    }
    __syncthreads();
    for (int i = tid; i < 640; i += 256) {
        int n = i / 10, j2 = i % 10;
        float s = fb2[j2];
        for (int j = 0; j < 64; ++j) s = fmaf(h1[n * 64 + j], fw2[j2 * 64 + j], s);
        out[i] = s;
    }
}

extern "C" void kernel_launch(void* const* d_in, const int* in_sizes, int n_in,
                              void* d_out, int out_size, void* d_ws, size_t ws_size,
                              hipStream_t stream) {
    const float* x   = (const float*)d_in[0];
    const float* w0  = (const float*)d_in[1];
    const float* b0  = (const float*)d_in[2];
    const float* w1  = (const float*)d_in[3];
    const float* b1  = (const float*)d_in[4];
    const float* w2  = (const float*)d_in[5];
    const float* b2  = (const float*)d_in[6];
    const float* w3  = (const float*)d_in[7];
    const float* b3  = (const float*)d_in[8];
    const float* w4  = (const float*)d_in[9];
    const float* b4  = (const float*)d_in[10];
    const float* w5  = (const float*)d_in[11];
    const float* b5  = (const float*)d_in[12];
    const float* fw1 = (const float*)d_in[13];
    const float* fb1 = (const float*)d_in[14];
    const float* fw2 = (const float*)d_in[15];
    const float* fb2 = (const float*)d_in[16];

    char* ws = (char*)d_ws;
    if (ws_size < 128827392ull) return;

    float* F0   = (float*)(ws + 0);
    u16*   WF1  = (u16*)(ws + 8192);
    u16*   WF2  = (u16*)(ws + 161792);
    u16*   WF3  = (u16*)(ws + 468992);
    u16*   WF4  = (u16*)(ws + 1083392);
    u16*   WF5  = (u16*)(ws + 2004992);
    float* MEANB= (float*)(ws + 2619392);
    float* XP   = (float*)(ws + 2635776);
    float* C5   = (float*)(ws + 5144576);
    u16*   A    = (u16*)(ws + 12369920);    // P1 / P3 / P5
    u16*   B    = (u16*)(ws + 87867392);    // P2 / P4
    const long P1LO = 14155776;   // 64*96*96*24
    const long P2LO = 10240000;   // 64*50*50*64
    const long P4LO = 4478976;    // 64*27*27*96

    // --- fused setup: XP border zero + transforms + pad_x + P1/P2 halo prep
    hipMemsetAsync(XP, 0, 2508800, stream);
    hipLaunchKernelGGL(setup_kernel, dim3((1993624 + 255) / 256), dim3(256), 0, stream,
                       w0, w1, w2, w3, w4, w5,
                       F0, WF1, WF2, WF3, WF4, WF5,
                       x, XP, A, P1LO, B, P2LO);

    // --- conv0 -> P1 (A) ---
    hipLaunchKernelGGL(conv0_kernel, dim3((64*92*23 + 255)/256), dim3(256), 0, stream,
                       XP, F0, b0, A, P1LO);

    // --- conv1 (+pool): P1 -> P2 [50][50][64] --- PMODE 0
    hipLaunchKernelGGL((conv_mfma_kernel<32, 24, 3, 3, 3, 2, 4, true, 0, 64, true, 0, false>),
                       dim3(1536), dim3(256), 0, stream,
                       A, P1LO, WF1, 38400, b1, B, P2LO, (float*)nullptr,
                       96, 96, 92, 92, 46, 46, 12, 2, 50, 50, 0);

    // --- conv2: P2 -> P3 (A) [50][50][64] --- PMODE 1, zeroes P3 halo itself
    hipLaunchKernelGGL((conv_mfma_kernel<64, 64, 3, 3, 3, 1, 4, false, 0, 64, true, 1, true>),
                       dim3(768), dim3(256), 0, stream,
                       B, P2LO, WF2, 76800, b2, A, P2LO, (float*)nullptr,
                       50, 50, 46, 46, 0, 0, 12, 1, 50, 50, 64 * 50 * 50);

    // --- conv3 (+pool): P3 -> P4 (B) [27][27][96] --- PMODE 0, zeroes P4 halo
    hipLaunchKernelGGL((conv_mfma_kernel<64, 64, 6, 3, 3, 2, 2, true, 0, 96, true, 0, true>),
                       dim3(768), dim3(256), 0, stream,
                       A, P2LO, WF3, 153600, b3, B, P4LO, (float*)nullptr,
                       50, 50, 46, 46, 23, 23, 12, 1, 27, 27, 64 * 27 * 27);

    // --- conv4: P4 -> P5 (A) [27][27][96] --- PMODE 1, zeroes P5 halo
    hipLaunchKernelGGL((conv_mfma_kernel<96, 96, 6, 3, 2, 2, 2, false, 0, 96, true, 1, true>),
                       dim3(384), dim3(256), 0, stream,
                       B, P4LO, WF4, 230400, b4, A, P4LO, (float*)nullptr,
                       27, 27, 23, 23, 0, 0, 6, 1, 27, 27, 64 * 27 * 27);

    // --- conv5: P5 -> C5 fp32 NHWC compact [21][21][64] --- PMODE 1
    hipLaunchKernelGGL((conv_mfma_kernel<96, 96, 4, 2, 2, 2, 2, false, 1, 96, false, 1, false>),
                       dim3(384), dim3(256), 0, stream,
                       A, P4LO, WF5, 153600, b5, (u16*)A, 0, C5,
                       27, 27, 21, 21, 0, 0, 6, 1, 27, 27, 0);

    // --- mean + fc ---
    hipLaunchKernelGGL(mean_nhwc_kernel, dim3(64), dim3(256), 0, stream, C5, MEANB);
    hipLaunchKernelGGL(fc_kernel, dim3(1), dim3(256), 0, stream,
                       MEANB, fw1, fb1, fw2, fb2, (float*)d_out);
}